// Round 15
// baseline (232.839 us; speedup 1.0000x reference)
//
#include <hip/hip_runtime.h>
#include <math.h>

#define B_ 8
#define C_ 256
#define N_ 9216
#define S_ 256
#define K_ 64
#define NCHUNK 36            // 9216 / 256
#define TILE_KS (K_ * S_)    // 16384
#define NC8 (N_ / 8)         // 1152 16B-cells per [*][N] bf16 row

typedef unsigned short ushort_t;
typedef __attribute__((ext_vector_type(8))) short bf16x8;
typedef __attribute__((ext_vector_type(4))) float f32x4;

static __device__ inline ushort_t f2bf(float x) {
    unsigned int u = __float_as_uint(x);
    unsigned int r = (u + 0x7fffu + ((u >> 16) & 1u)) >> 16;
    return (ushort_t)r;
}
static __device__ inline float bf2f(ushort_t u) {
    return __uint_as_float(((unsigned int)u) << 16);
}
// packed bf16 convert (RNE, same as f2bf): lo -> bits[15:0], hi -> bits[31:16]
static __device__ inline unsigned int cvtpk(float lo, float hi) {
    unsigned int r;
    asm("v_cvt_pk_bf16_f32 %0, %1, %2" : "=v"(r) : "v"(lo), "v"(hi));
    return r;
}

// exp-weight one 8-bf16 cell (row-constant max/invsum in s)
static __device__ inline uint4 expcell(uint4 u, float2 s) {
    uint4 r;
    unsigned int* up = (unsigned int*)&u;
    unsigned int* rp = (unsigned int*)&r;
#pragma unroll
    for (int q = 0; q < 4; ++q) {
        unsigned int x = up[q];
        float lo = __uint_as_float((x & 0xffffu) << 16);
        float hi = __uint_as_float(x & 0xffff0000u);
        rp[q] = cvtpk(__expf(lo - s.x) * s.y, __expf(hi - s.x) * s.y);
    }
    return r;
}

// ---------------- fold BN scale into W -> bf16 in STAGING-COALESCED layout Wt.
__global__ __launch_bounds__(256) void prep_w(
    const float* __restrict__ phi_w, const float* __restrict__ phi_g, const float* __restrict__ phi_b,
    const float* __restrict__ phi_m, const float* __restrict__ phi_v,
    const float* __restrict__ th_w, const float* __restrict__ th_g, const float* __restrict__ th_b,
    const float* __restrict__ th_m, const float* __restrict__ th_v,
    const float* __restrict__ ro_w, const float* __restrict__ ro_g, const float* __restrict__ ro_b,
    const float* __restrict__ ro_m, const float* __restrict__ ro_v,
    const float* __restrict__ va_w, const float* __restrict__ va_g, const float* __restrict__ va_b,
    const float* __restrict__ va_m, const float* __restrict__ va_v,
    ushort_t* __restrict__ Wt, float* __restrict__ be)
{
    const int o = blockIdx.x;  // 0..831
    const int t = threadIdx.x; // = c
    const float *src, *g, *bb, *mm, *vv; int orel;
    if (o < 64)       { src = phi_w; g = phi_g; bb = phi_b; mm = phi_m; vv = phi_v; orel = o; }
    else if (o < 320) { src = th_w;  g = th_g;  bb = th_b;  mm = th_m;  vv = th_v;  orel = o - 64; }
    else if (o < 576) { src = ro_w;  g = ro_g;  bb = ro_b;  mm = ro_m;  vv = ro_v;  orel = o - 320; }
    else              { src = va_w;  g = va_g;  bb = va_b;  mm = va_m;  vv = va_v;  orel = o - 576; }
    const float s = g[orel] / sqrtf(vv[orel] + 1e-5f);
    const int ot = o >> 6, os = (o >> 4) & 3, st = t >> 5;
    const size_t flat = ((((size_t)ot * 8 + st) * 4 + os) * 64 + ((t >> 3) & 3) * 16 + (o & 15)) * 8 + (t & 7);
    Wt[flat] = f2bf(src[orel * C_ + t] * s);
    if (t == 0) be[o] = bb[orel] - mm[orel] * s;
}

// ---------------- X[b][c][n] fp32 -> Xs bf16 in STAGING-COALESCED layout
__global__ __launch_bounds__(256) void xpose(
    const float* __restrict__ X, ushort_t* __restrict__ Xs)
{
    __shared__ float T[64][65];
    const int b = blockIdx.z, c0 = blockIdx.y * 64, n0 = blockIdx.x * 64;
    const int t = threadIdx.x;
#pragma unroll
    for (int p = 0; p < 4; ++p) {
        int c = p * 16 + (t >> 4), nn = (t & 15) * 4;
        float4 v = *(const float4*)&X[((size_t)b * C_ + c0 + c) * N_ + n0 + nn];
        T[c][nn] = v.x; T[c][nn + 1] = v.y; T[c][nn + 2] = v.z; T[c][nn + 3] = v.w;
    }
    __syncthreads();
#pragma unroll
    for (int p = 0; p < 4; ++p) {
        int nn = p * 16 + (t >> 4), cl = (t & 15) * 4;
        uint2 uu;
        uu.x = cvtpk(T[cl][nn], T[cl + 1][nn]);
        uu.y = cvtpk(T[cl + 2][nn], T[cl + 3][nn]);
        const int n = n0 + nn, c = c0 + cl;
        const int nt = n >> 8, nr = n & 255;
        const int st = c >> 5, g8 = (c >> 3) & 3, e = c & 7;  // e in {0,4}
        const size_t base = ((((size_t)b * 36 + nt) * 8 + st) * 1024
                             + (nr >> 4) * 64 + g8 * 16 + (nr & 15)) * 8 + e;
        *(uint2*)&Xs[base] = uu;
    }
}

// ---------------- fused bf16-MFMA projection (validated R12/R14 shape, FROZEN)
__global__ __launch_bounds__(256) void proj_mfma_all(
    const ushort_t* __restrict__ Wt, const float* __restrict__ be,
    const ushort_t* __restrict__ Xs,
    ushort_t* __restrict__ Pbf, ushort_t* __restrict__ Tbf,
    ushort_t* __restrict__ Vbf, ushort_t* __restrict__ Rt)
{
    __shared__ short sm[9216];  // 18 KB: epilogue transpose tiles only
    const int t = threadIdx.x;
    const int l = t & 63, w = t >> 6;
    const int idx = blockIdx.x;          // 0..3743
    const int xcd = idx & 7, pos = idx >> 3;
    const int vid = xcd * 468 + pos;     // 468 = 36*13 blocks per XCD chunk
    const int ot  = vid % 13;
    const int r   = vid / 13;            // 0..287
    const int b   = r / 36;
    const int nt  = r % 36;
    const int n0  = nt * 256;
    const int o0  = ot * 64;

    const bf16x8* Wv = (const bf16x8*)Wt;
    const bf16x8* Xf = (const bf16x8*)Xs;
    const size_t xbase = ((size_t)b * 36 + nt) * 8192;  // 8 stages x 1024 cells
    const size_t wbase = (size_t)ot * 2048;             // 8 stages x 256 cells
    const int boff = (l >> 4) * 16 + (l & 15);          // == l (coalesced)

    f32x4 zr = {0.f, 0.f, 0.f, 0.f};
    f32x4 acc[4][4];
#pragma unroll
    for (int i = 0; i < 4; ++i)
#pragma unroll
        for (int j = 0; j < 4; ++j) acc[i][j] = zr;

    // prologue: stage-0 fragments
    bf16x8 A0[4], B0[4];
#pragma unroll
    for (int os = 0; os < 4; ++os) A0[os] = Wv[wbase + os * 64 + l];
#pragma unroll
    for (int j = 0; j < 4; ++j)   B0[j]  = Xf[xbase + (w * 4 + j) * 64 + boff];

#pragma unroll
    for (int st = 0; st < 8; ++st) {
        bf16x8 A1[4], B1[4];
        if (st < 7) {  // prefetch next stage (hides L2 latency under MFMA)
#pragma unroll
            for (int os = 0; os < 4; ++os)
                A1[os] = Wv[wbase + (st + 1) * 256 + os * 64 + l];
#pragma unroll
            for (int j = 0; j < 4; ++j)
                B1[j] = Xf[xbase + (size_t)(st + 1) * 1024 + (w * 4 + j) * 64 + boff];
        }
#pragma unroll
        for (int os = 0; os < 4; ++os)
#pragma unroll
            for (int j = 0; j < 4; ++j)
                acc[os][j] = __builtin_amdgcn_mfma_f32_16x16x32_bf16(A0[os], B0[j], acc[os][j], 0, 0, 0);
#pragma unroll
        for (int os = 0; os < 4; ++os) A0[os] = A1[os];
#pragma unroll
        for (int j = 0; j < 4; ++j)   B0[j]  = B1[j];
    }

    // epilogue (block-uniform branch on o0); LDS 18KB; cvt_pk bf16 converts
    if (o0 >= 320 && o0 < 576) {
        const int od = o0 - 320;
        ushort_t* Tt = (ushort_t*)sm + w * (32 * 72);
#pragma unroll
        for (int half = 0; half < 2; ++half) {
            __syncthreads();
#pragma unroll
            for (int jj = 0; jj < 2; ++jj) {
                const int j = half * 2 + jj;
                const int row = jj * 16 + (l & 15);
#pragma unroll
                for (int os = 0; os < 4; ++os) {
                    const int scol0 = os * 16 + (l >> 4) * 4;  // multiple of 4
                    const float b0 = be[o0 + scol0], b1 = be[o0 + scol0 + 1];
                    const float b2 = be[o0 + scol0 + 2], b3 = be[o0 + scol0 + 3];
                    unsigned int p0 = cvtpk(fmaxf(acc[os][j][0] + b0, 0.f),
                                            fmaxf(acc[os][j][1] + b1, 0.f));
                    unsigned int p1 = cvtpk(fmaxf(acc[os][j][2] + b2, 0.f),
                                            fmaxf(acc[os][j][3] + b3, 0.f));
                    *(unsigned int*)&Tt[row * 72 + scol0]     = p0;
                    *(unsigned int*)&Tt[row * 72 + scol0 + 2] = p1;
                }
            }
            __syncthreads();
#pragma unroll
            for (int p = 0; p < 4; ++p) {
                const int lrow = p * 8 + (l >> 3);
                uint4 v = *(const uint4*)&Tt[lrow * 72 + (l & 7) * 8];
                *(uint4*)&Rt[((size_t)b * N_ + n0 + w * 64 + half * 32 + lrow) * 256 + od + (l & 7) * 8] = v;
            }
        }
    } else {
        ushort_t* dst; int od, osz;
        if (o0 < 64)       { dst = Pbf; od = o0;       osz = 64;  }
        else if (o0 < 320) { dst = Tbf; od = o0 - 64;  osz = 256; }
        else               { dst = Vbf; od = o0 - 576; osz = 256; }
        ushort_t* Tw = (ushort_t*)sm + w * (32 * 68);
        const int c = l & 15;
#pragma unroll
        for (int half = 0; half < 2; ++half) {
            __syncthreads();
#pragma unroll
            for (int osl = 0; osl < 2; ++osl) {
                const int os = half * 2 + osl;
#pragma unroll
                for (int r2 = 0; r2 < 4; ++r2) {
                    const int lrow = osl * 16 + (l >> 4) * 4 + r2;
                    const int orow = half * 32 + lrow;
                    const float bias = be[o0 + orow];
                    unsigned int p0 = cvtpk(fmaxf(acc[os][0][r2] + bias, 0.f),
                                            fmaxf(acc[os][1][r2] + bias, 0.f));
                    unsigned int p1 = cvtpk(fmaxf(acc[os][2][r2] + bias, 0.f),
                                            fmaxf(acc[os][3][r2] + bias, 0.f));
                    Tw[lrow * 68 + c]      = (ushort_t)p0;
                    Tw[lrow * 68 + 16 + c] = (ushort_t)(p0 >> 16);
                    Tw[lrow * 68 + 32 + c] = (ushort_t)p1;
                    Tw[lrow * 68 + 48 + c] = (ushort_t)(p1 >> 16);
                }
            }
            __syncthreads();
#pragma unroll
            for (int i = 0; i < 8; ++i) {
                const int lrow = i * 4 + (l >> 4);
                ushort4 v = *(const ushort4*)&Tw[lrow * 68 + (l & 15) * 4];
                *(ushort4*)&dst[((size_t)(b * osz + od + half * 32 + lrow)) * N_ + n0 + w * 64 + (l & 15) * 4] = v;
            }
        }
    }
}

// ---------------- theta row stats: st2[row] = (max, 1/sum(exp(x-max))) over N
__global__ __launch_bounds__(256) void rowstat_n(
    const ushort_t* __restrict__ T, float* __restrict__ st2)
{
    const int row = blockIdx.x;  // b*256 + s
    const ushort4* p = (const ushort4*)(T + (size_t)row * N_);
    const int t = threadIdx.x;
    float v[36];
    float mx = -INFINITY;
#pragma unroll
    for (int i = 0; i < 9; ++i) {
        ushort4 u = p[t + i * 256];
        v[i * 4 + 0] = bf2f(u.x); v[i * 4 + 1] = bf2f(u.y);
        v[i * 4 + 2] = bf2f(u.z); v[i * 4 + 3] = bf2f(u.w);
        mx = fmaxf(mx, fmaxf(fmaxf(v[i * 4], v[i * 4 + 1]), fmaxf(v[i * 4 + 2], v[i * 4 + 3])));
    }
    __shared__ float red[256];
    red[t] = mx; __syncthreads();
    for (int s2 = 128; s2 > 0; s2 >>= 1) {
        if (t < s2) red[t] = fmaxf(red[t], red[t + s2]);
        __syncthreads();
    }
    mx = red[0]; __syncthreads();
    float sum = 0.f;
#pragma unroll
    for (int i = 0; i < 36; ++i) sum += __expf(v[i] - mx);
    red[t] = sum; __syncthreads();
    for (int s2 = 128; s2 > 0; s2 >>= 1) {
        if (t < s2) red[t] += red[t + s2];
        __syncthreads();
    }
    if (t == 0) ((float2*)st2)[row] = make_float2(mx, 1.0f / red[0]);
}

// ---------------- MFMA: P[chunk][b][k][s] = sum_{n in chunk} A[b,k,n] * w(Bm)[b,s,n]
// obf16: write partials as bf16 (discrib path; positive summands, error crushed by softmax)
__global__ __launch_bounds__(256) void ks_mfma(
    const ushort_t* __restrict__ A, const ushort_t* __restrict__ Bm,
    const float* __restrict__ st2, float* __restrict__ P, int obf16)
{
    __shared__ short sm[32768];
    const int t = threadIdx.x;
    const int l = t & 63, w = t >> 6;
    const int chunk = blockIdx.x, b = blockIdx.y;
    const int ccell = chunk * 32;

    const uint4* Av = (const uint4*)A;
    const uint4* Bv = (const uint4*)Bm;
    const float2* S2 = (const float2*)st2;
    uint4* smv = (uint4*)sm;
    const bool doexp = (st2 != nullptr);

    uint4 wreg[8], xreg[8];
    float2 sreg[8];
#pragma unroll
    for (int i = 0; i < 8; ++i) {
        int cell = i * 256 + t;
        int osub = cell >> 9, g = (cell >> 4) & 31, oi = cell & 15;
        wreg[i] = Av[(size_t)(b * 64 + osub * 16 + oi) * NC8 + ccell + g];
    }
#pragma unroll
    for (int i = 0; i < 8; ++i) {
        int cell = i * 256 + t;
        int s = cell >> 7, g8 = (cell >> 4) & 7, ni = cell & 15;
        int row = s * 16 + ni;
        xreg[i] = Bv[(size_t)(b * 256 + row) * NC8 + ccell + g8];
        if (doexp) sreg[i] = S2[b * 256 + row];
    }
#pragma unroll
    for (int i = 0; i < 8; ++i) smv[i * 256 + t] = wreg[i];
#pragma unroll
    for (int i = 0; i < 8; ++i) smv[2048 + i * 256 + t] = doexp ? expcell(xreg[i], sreg[i]) : xreg[i];
    __syncthreads();

    f32x4 zr = {0.f, 0.f, 0.f, 0.f};
    f32x4 acc[4][4];
#pragma unroll
    for (int i = 0; i < 4; ++i)
#pragma unroll
        for (int j = 0; j < 4; ++j) acc[i][j] = zr;

    const bf16x8* smW = (const bf16x8*)sm;
    const bf16x8* smX = (const bf16x8*)(sm + 16384);

    for (int st = 0; st < 4; ++st) {
        if (st < 3) {
#pragma unroll
            for (int i = 0; i < 8; ++i) {
                int cell = i * 256 + t;
                int s = cell >> 7, g8 = (cell >> 4) & 7, ni = cell & 15;
                int row = s * 16 + ni;
                xreg[i] = Bv[(size_t)(b * 256 + row) * NC8 + ccell + (st + 1) * 8 + g8];
            }
        }
#pragma unroll
        for (int kgl = 0; kgl < 2; ++kgl) {
            const int kg = st * 2 + kgl;
            bf16x8 Af[4], Bf[4];
#pragma unroll
            for (int os = 0; os < 4; ++os)
                Af[os] = smW[(os * 32 + kg * 4 + (l >> 4)) * 16 + (l & 15)];
#pragma unroll
            for (int j = 0; j < 4; ++j)
                Bf[j] = smX[((w * 4 + j) * 8 + kgl * 4 + (l >> 4)) * 16 + (l & 15)];
#pragma unroll
            for (int os = 0; os < 4; ++os)
#pragma unroll
                for (int j = 0; j < 4; ++j)
                    acc[os][j] = __builtin_amdgcn_mfma_f32_16x16x32_bf16(Af[os], Bf[j], acc[os][j], 0, 0, 0);
        }
        __syncthreads();
        if (st < 3) {
#pragma unroll
            for (int i = 0; i < 8; ++i) smv[2048 + i * 256 + t] = doexp ? expcell(xreg[i], sreg[i]) : xreg[i];
            __syncthreads();
        }
    }

    if (obf16) {
        ushort_t* Pb = (ushort_t*)P + ((size_t)(chunk * B_ + b)) * TILE_KS;
#pragma unroll
        for (int os = 0; os < 4; ++os)
#pragma unroll
            for (int r = 0; r < 4; ++r) {
                const int k = os * 16 + (l >> 4) * 4 + r;
                unsigned int p0 = cvtpk(acc[os][0][r], acc[os][1][r]);
                unsigned int p1 = cvtpk(acc[os][2][r], acc[os][3][r]);
                Pb[k * 256 + w * 64 + 0  + (l & 15)] = (ushort_t)p0;
                Pb[k * 256 + w * 64 + 16 + (l & 15)] = (ushort_t)(p0 >> 16);
                Pb[k * 256 + w * 64 + 32 + (l & 15)] = (ushort_t)p1;
                Pb[k * 256 + w * 64 + 48 + (l & 15)] = (ushort_t)(p1 >> 16);
            }
    } else {
        float* Pb = P + ((size_t)(chunk * B_ + b)) * TILE_KS;
#pragma unroll
        for (int os = 0; os < 4; ++os)
#pragma unroll
            for (int r = 0; r < 4; ++r) {
                const int k = os * 16 + (l >> 4) * 4 + r;
#pragma unroll
                for (int j = 0; j < 4; ++j)
                    Pb[k * 256 + (w * 4 + j) * 16 + (l & 15)] = acc[os][j][r];
            }
    }
}

// ---------------- MFMA: Qraw[b][n][k](bf16) = sum_s Dbf[b,k,s] * softmax_s(Rt)[b,n,s]
// Per-n softmax stats computed IN-BLOCK (wave-per-row coalesced pass; replaces the
// rowstat_rt kernel + its 37.7MB HBM pass); fused nrm2 atomics.
__global__ __launch_bounds__(256) void qt_mfma(
    const ushort_t* __restrict__ Dbf,  // [b][64][256]
    const ushort_t* __restrict__ Rraw, // [b][N][256] raw rou
    ushort_t* __restrict__ Qraw,       // [b][N][64] bf16
    float* __restrict__ Nrm)           // [b][64], pre-zeroed
{
    __shared__ short sm[33792];        // 64KB staging/epilogue + 2KB row stats
    float* stat = (float*)sm + 16384;  // [0..255]=max, [256..511]=invsum (above 64KB)
    const int t = threadIdx.x;
    const int l = t & 63, w = t >> 6;
    const int b = blockIdx.x / 36;
    const int n0 = (blockIdx.x % 36) * 256;

    const uint4* Av = (const uint4*)Dbf;
    const uint4* Xv = (const uint4*)Rraw;
    uint4* smv = (uint4*)sm;

    uint4 wreg[8], xreg[8];
#pragma unroll
    for (int i = 0; i < 8; ++i) {
        int cell = i * 256 + t;
        int osub = cell >> 9, g = (cell >> 4) & 31, oi = cell & 15;
        wreg[i] = Av[(size_t)(b * 64 + osub * 16 + oi) * 32 + g];
    }
#pragma unroll
    for (int i = 0; i < 8; ++i) {
        int cell = i * 256 + t;
        int s = cell >> 7, g8 = (cell >> 4) & 7, ni = cell & 15;
        xreg[i] = Xv[((size_t)b * N_ + n0 + s * 16 + ni) * 32 + g8];
    }

    // pre-phase: wave w computes softmax stats for local rows [w*64, w*64+64)
    for (int r = 0; r < 64; ++r) {
        const int nl = w * 64 + r;
        const uint2* prow = (const uint2*)(Rraw + ((size_t)b * N_ + n0 + nl) * 256);
        uint2 u = prow[l];  // 64 lanes x 8B = full 512B row
        float f0 = bf2f((ushort_t)u.x), f1 = bf2f(u.x >> 16);
        float f2 = bf2f((ushort_t)u.y), f3 = bf2f(u.y >> 16);
        float mx = fmaxf(fmaxf(f0, f1), fmaxf(f2, f3));
#pragma unroll
        for (int m = 1; m < 64; m <<= 1) mx = fmaxf(mx, __shfl_xor(mx, m));
        float s = __expf(f0 - mx) + __expf(f1 - mx) + __expf(f2 - mx) + __expf(f3 - mx);
#pragma unroll
        for (int m = 1; m < 64; m <<= 1) s += __shfl_xor(s, m);
        if (l == 0) { stat[nl] = mx; stat[256 + nl] = 1.0f / s; }
    }
    __syncthreads();

#pragma unroll
    for (int i = 0; i < 8; ++i) smv[i * 256 + t] = wreg[i];
#pragma unroll
    for (int i = 0; i < 8; ++i) {
        int cell = i * 256 + t;
        int row = (cell >> 7) * 16 + (cell & 15);
        smv[2048 + i * 256 + t] = expcell(xreg[i], make_float2(stat[row], stat[256 + row]));
    }
    __syncthreads();

    f32x4 zr = {0.f, 0.f, 0.f, 0.f};
    f32x4 acc[4][4];
#pragma unroll
    for (int i = 0; i < 4; ++i)
#pragma unroll
        for (int j = 0; j < 4; ++j) acc[i][j] = zr;

    const bf16x8* smW = (const bf16x8*)sm;
    const bf16x8* smX = (const bf16x8*)(sm + 16384);

    for (int st = 0; st < 4; ++st) {
        if (st < 3) {
#pragma unroll
            for (int i = 0; i < 8; ++i) {
                int cell = i * 256 + t;
                int s = cell >> 7, g8 = (cell >> 4) & 7, ni = cell & 15;
                xreg[i] = Xv[((size_t)b * N_ + n0 + s * 16 + ni) * 32 + (st + 1) * 8 + g8];
            }
        }
#pragma unroll
        for (int kgl = 0; kgl < 2; ++kgl) {
            const int kg = st * 2 + kgl;
            bf16x8 Af[4], Bf[4];
#pragma unroll
            for (int os = 0; os < 4; ++os)
                Af[os] = smW[(os * 32 + kg * 4 + (l >> 4)) * 16 + (l & 15)];
#pragma unroll
            for (int j = 0; j < 4; ++j)
                Bf[j] = smX[((w * 4 + j) * 8 + kgl * 4 + (l >> 4)) * 16 + (l & 15)];
#pragma unroll
            for (int os = 0; os < 4; ++os)
#pragma unroll
                for (int j = 0; j < 4; ++j)
                    acc[os][j] = __builtin_amdgcn_mfma_f32_16x16x32_bf16(Af[os], Bf[j], acc[os][j], 0, 0, 0);
        }
        __syncthreads();
        if (st < 3) {
#pragma unroll
            for (int i = 0; i < 8; ++i) {
                int cell = i * 256 + t;
                int row = (cell >> 7) * 16 + (cell & 15);
                smv[2048 + i * 256 + t] = expcell(xreg[i], make_float2(stat[row], stat[256 + row]));
            }
            __syncthreads();
        }
    }

    // epilogue: nrm2 partials + [n][k] transposed bf16 stores
    float* snrm = (float*)sm + 9216;
    __syncthreads();
    if (t < 64) snrm[t] = 0.f;
    __syncthreads();
#pragma unroll
    for (int os = 0; os < 4; ++os)
#pragma unroll
        for (int r = 0; r < 4; ++r) {
            float p = 0.f;
#pragma unroll
            for (int j = 0; j < 4; ++j) p = fmaf(acc[os][j][r], acc[os][j][r], p);
#pragma unroll
            for (int m = 1; m < 16; m <<= 1) p += __shfl_xor(p, m);
            if ((l & 15) == 0) atomicAdd(&snrm[os * 16 + (l >> 4) * 4 + r], p);
        }
    float* Tw = (float*)sm + w * 2304;  // per-wave [32][72]
#pragma unroll
    for (int h = 0; h < 2; ++h) {
        __syncthreads();
#pragma unroll
        for (int os = 0; os < 4; ++os)
#pragma unroll
            for (int r = 0; r < 4; ++r) {
                const int kcol = os * 16 + (l >> 4) * 4 + r;
#pragma unroll
                for (int jj = 0; jj < 2; ++jj)
                    Tw[(jj * 16 + (l & 15)) * 72 + kcol] = acc[os][h * 2 + jj][r];
            }
        __syncthreads();
#pragma unroll
        for (int i = 0; i < 8; ++i) {
            const int lrow = i * 4 + (l >> 4);
            f32x4 v = *(const f32x4*)&Tw[lrow * 72 + (l & 15) * 4];
            uint2 uu;
            uu.x = cvtpk(v[0], v[1]);
            uu.y = cvtpk(v[2], v[3]);
            *(uint2*)&Qraw[((size_t)b * N_ + n0 + w * 64 + h * 32 + lrow) * 64 + (l & 15) * 4] = uu;
        }
    }
    __syncthreads();
    if (t < 64) atomicAdd(&Nrm[b * 64 + t], snrm[t]);
}

// ---------------- partial-sum reductions over NCHUNK
__global__ __launch_bounds__(256) void chunk_reduce_bf(
    const ushort_t* __restrict__ P, ushort_t* __restrict__ outb)
{
    const int i2 = blockIdx.x * 256 + threadIdx.x;  // uint2 cell = 4 bf16
    float s0 = 0.f, s1 = 0.f, s2 = 0.f, s3 = 0.f;
#pragma unroll
    for (int c = 0; c < NCHUNK; ++c) {
        uint2 u = ((const uint2*)P)[(size_t)c * (B_ * TILE_KS / 4) + i2];
        s0 += bf2f((ushort_t)u.x); s1 += bf2f(u.x >> 16);
        s2 += bf2f((ushort_t)u.y); s3 += bf2f(u.y >> 16);
    }
    uint2 o;
    o.x = cvtpk(s0, s1);
    o.y = cvtpk(s2, s3);
    ((uint2*)outb)[i2] = o;
}
__global__ __launch_bounds__(256) void chunk_reduce_f(
    const float* __restrict__ P, float* __restrict__ outf)
{
    const int i4 = blockIdx.x * 256 + threadIdx.x;
    float4 s = make_float4(0.f, 0.f, 0.f, 0.f);
#pragma unroll
    for (int c = 0; c < NCHUNK; ++c) {
        float4 v = ((const float4*)P)[(size_t)c * (B_ * TILE_KS / 4) + i4];
        s.x += v.x; s.y += v.y; s.z += v.z; s.w += v.w;
    }
    ((float4*)outf)[i4] = s;
}

// ---------------- Q = softmax_k(Qraw * invn); write Qout[b][n][k] fp32 + Qbf[b][k][n] bf16
__global__ __launch_bounds__(256) void q_final(
    const ushort_t* __restrict__ Qraw, const float* __restrict__ Nrm,
    float* __restrict__ Qout, ushort_t* __restrict__ Qbf)
{
    __shared__ ushort_t Tq[64 * 256];
    __shared__ float invn[64];
    const int b = blockIdx.y;
    const int n0 = blockIdx.x * 256;
    const int t = threadIdx.x;
    const int l = t & 63, w = t >> 6;
    if (t < 64) invn[t] = 1.0f / fmaxf(sqrtf(Nrm[b * 64 + t]), 1e-12f);
    __syncthreads();
    const uint4* q4 = (const uint4*)(Qraw + ((size_t)b * N_ + n0 + t) * 64);
    float q[64];
#pragma unroll
    for (int kk = 0; kk < 8; ++kk) {
        uint4 u = q4[kk];
        q[kk * 8 + 0] = bf2f((ushort_t)u.x); q[kk * 8 + 1] = bf2f(u.x >> 16);
        q[kk * 8 + 2] = bf2f((ushort_t)u.y); q[kk * 8 + 3] = bf2f(u.y >> 16);
        q[kk * 8 + 4] = bf2f((ushort_t)u.z); q[kk * 8 + 5] = bf2f(u.z >> 16);
        q[kk * 8 + 6] = bf2f((ushort_t)u.w); q[kk * 8 + 7] = bf2f(u.w >> 16);
    }
    float mx = -INFINITY;
#pragma unroll
    for (int k = 0; k < 64; ++k) { q[k] *= invn[k]; mx = fmaxf(mx, q[k]); }
    float sum = 0.f;
#pragma unroll
    for (int k = 0; k < 64; ++k) { q[k] = __expf(q[k] - mx); sum += q[k]; }
    const float inv = 1.0f / sum;
    const size_t base = ((size_t)b * N_ + n0 + t) * 64;
#pragma unroll
    for (int kk = 0; kk < 16; ++kk) {
        f32x4 v = {q[kk * 4] * inv, q[kk * 4 + 1] * inv, q[kk * 4 + 2] * inv, q[kk * 4 + 3] * inv};
        *(f32x4*)&Qout[base + kk * 4] = v;
        q[kk * 4] = v[0]; q[kk * 4 + 1] = v[1]; q[kk * 4 + 2] = v[2]; q[kk * 4 + 3] = v[3];
    }
#pragma unroll
    for (int k = 0; k < 64; ++k) Tq[k * 256 + t] = f2bf(q[k]);
    __syncthreads();
#pragma unroll
    for (int kk = 0; kk < 16; ++kk) {
        const int k = kk * 4 + w;
        ushort4 v = *(const ushort4*)&Tq[k * 256 + l * 4];
        *(ushort4*)&Qbf[((size_t)b * 64 + k) * N_ + n0 + l * 4] = v;
    }
}

// ---------------- Z[b,s,k] = ZnT[b,k,s] / l2norm over s (qsum cancels in l2norm)
__global__ __launch_bounds__(256) void z_final(
    const float* __restrict__ ZnT, float* __restrict__ Z)
{
    __shared__ float red[256];
    __shared__ float invn[64];
    const int b = blockIdx.x;
    const int t = threadIdx.x;
    const float* Zb = ZnT + (size_t)b * TILE_KS;
    {
        const int k = t >> 2, qq = t & 3;
        float ss = 0.f;
        for (int j = 0; j < 64; ++j) {
            float v = Zb[k * 256 + qq * 64 + j];
            ss = fmaf(v, v, ss);
        }
        red[t] = ss;
    }
    __syncthreads();
    if ((t & 3) == 0) {
        float tot = red[t] + red[t + 1] + red[t + 2] + red[t + 3];
        invn[t >> 2] = 1.0f / fmaxf(sqrtf(tot), 1e-12f);
    }
    __syncthreads();
    {
        const int k = t & 63, w = t >> 6;
        const float sc = invn[k];
        for (int j = 0; j < 64; ++j) {
            int s = w * 64 + j;
            Z[((size_t)b * 256 + s) * 64 + k] = Zb[k * 256 + s] * sc;
        }
    }
}

extern "C" void kernel_launch(void* const* d_in, const int* in_sizes, int n_in,
                              void* d_out, int out_size, void* d_ws, size_t ws_size,
                              hipStream_t stream)
{
    const float* X       = (const float*)d_in[0];
    const float* phi_w   = (const float*)d_in[1];
    const float* phi_g   = (const float*)d_in[2];
    const float* phi_b   = (const float*)d_in[3];
    const float* phi_m   = (const float*)d_in[4];
    const float* phi_v   = (const float*)d_in[5];
    const float* theta_w = (const float*)d_in[6];
    const float* theta_g = (const float*)d_in[7];
    const float* theta_b = (const float*)d_in[8];
    const float* theta_m = (const float*)d_in[9];
    const float* theta_v = (const float*)d_in[10];
    const float* rou_w   = (const float*)d_in[11];
    const float* rou_g   = (const float*)d_in[12];
    const float* rou_b   = (const float*)d_in[13];
    const float* rou_m   = (const float*)d_in[14];
    const float* rou_v   = (const float*)d_in[15];
    const float* val_w   = (const float*)d_in[16];
    const float* val_g   = (const float*)d_in[17];
    const float* val_b   = (const float*)d_in[18];
    const float* val_m   = (const float*)d_in[19];
    const float* val_v   = (const float*)d_in[20];

    float* ws = (float*)d_ws;
    size_t off = 0;
    ushort_t* Xs  = (ushort_t*)(ws + off); off += (size_t)B_ * N_ * C_ / 2;
    ushort_t* Wt  = (ushort_t*)(ws + off); off += 832 * C_ / 2;
    float* be     = ws + off; off += 832;
    float* st2    = ws + off; off += 2 * B_ * 256;
    ushort_t* Pbf = (ushort_t*)(ws + off); off += (size_t)B_ * 64 * N_ / 2;
    ushort_t* Tbf = (ushort_t*)(ws + off); off += (size_t)B_ * 256 * N_ / 2;
    ushort_t* Vbf = (ushort_t*)(ws + off); off += (size_t)B_ * 256 * N_ / 2;
    ushort_t* Rt  = (ushort_t*)(ws + off); off += (size_t)B_ * N_ * 256 / 2;
    ushort_t* Qbf = (ushort_t*)(ws + off); off += (size_t)B_ * 64 * N_ / 2;
    ushort_t* Dbf = (ushort_t*)(ws + off); off += (size_t)B_ * 64 * 256 / 2;
    float* part   = ws + off; off += (size_t)NCHUNK * B_ * TILE_KS;
    ushort_t* Qraw = (ushort_t*)(ws + off); off += (size_t)B_ * N_ * 64 / 2;
    float* ZnT    = ws + off; off += (size_t)B_ * TILE_KS;
    float* Nrm    = ws + off; off += B_ * 64;

    float* Zout = (float*)d_out;                  // B*S*K
    float* Qout = Zout + (size_t)B_ * S_ * K_;    // B*N*K

    hipMemsetAsync(Nrm, 0, B_ * 64 * sizeof(float), stream);

    prep_w<<<832, 256, 0, stream>>>(phi_w, phi_g, phi_b, phi_m, phi_v,
                                    theta_w, theta_g, theta_b, theta_m, theta_v,
                                    rou_w, rou_g, rou_b, rou_m, rou_v,
                                    val_w, val_g, val_b, val_m, val_v, Wt, be);
    xpose<<<dim3(N_ / 64, C_ / 64, B_), 256, 0, stream>>>(X, Xs);

    proj_mfma_all<<<3744, 256, 0, stream>>>(Wt, be, Xs, Pbf, Tbf, Vbf, Rt);

    rowstat_n<<<B_ * 256, 256, 0, stream>>>(Tbf, st2);

    ks_mfma<<<dim3(NCHUNK, B_), 256, 0, stream>>>(Pbf, Tbf, st2, part, 1);
    chunk_reduce_bf<<<B_ * TILE_KS / 1024, 256, 0, stream>>>((const ushort_t*)part, Dbf);

    qt_mfma<<<36 * B_, 256, 0, stream>>>(Dbf, Rt, Qraw, Nrm);
    q_final<<<dim3(36, B_), 256, 0, stream>>>(Qraw, Nrm, Qout, Qbf);

    ks_mfma<<<dim3(NCHUNK, B_), 256, 0, stream>>>(Qbf, Vbf, (const float*)nullptr, part, 0);
    chunk_reduce_f<<<B_ * TILE_KS / 1024, 256, 0, stream>>>(part, ZnT);
    z_final<<<B_, 256, 0, stream>>>(ZnT, Zout);
}

// Round 16
// 196.726 us; speedup vs baseline: 1.1836x; 1.1836x over previous
//
#include <hip/hip_runtime.h>
#include <math.h>

#define B_ 8
#define C_ 256
#define N_ 9216
#define S_ 256
#define K_ 64
#define NCHUNK 36            // 9216 / 256
#define TILE_KS (K_ * S_)    // 16384
#define NC8 (N_ / 8)         // 1152 16B-cells per [*][N] bf16 row

typedef unsigned short ushort_t;
typedef __attribute__((ext_vector_type(8))) short bf16x8;
typedef __attribute__((ext_vector_type(4))) float f32x4;

static __device__ inline ushort_t f2bf(float x) {
    unsigned int u = __float_as_uint(x);
    unsigned int r = (u + 0x7fffu + ((u >> 16) & 1u)) >> 16;
    return (ushort_t)r;
}
static __device__ inline float bf2f(ushort_t u) {
    return __uint_as_float(((unsigned int)u) << 16);
}
// packed bf16 convert (RNE, same as f2bf): lo -> bits[15:0], hi -> bits[31:16]
static __device__ inline unsigned int cvtpk(float lo, float hi) {
    unsigned int r;
    asm("v_cvt_pk_bf16_f32 %0, %1, %2" : "=v"(r) : "v"(lo), "v"(hi));
    return r;
}

// exp-weight one 8-bf16 cell (row-constant max/invsum in s)
static __device__ inline uint4 expcell(uint4 u, float2 s) {
    uint4 r;
    unsigned int* up = (unsigned int*)&u;
    unsigned int* rp = (unsigned int*)&r;
#pragma unroll
    for (int q = 0; q < 4; ++q) {
        unsigned int x = up[q];
        float lo = __uint_as_float((x & 0xffffu) << 16);
        float hi = __uint_as_float(x & 0xffff0000u);
        rp[q] = cvtpk(__expf(lo - s.x) * s.y, __expf(hi - s.x) * s.y);
    }
    return r;
}

// ---------------- fold BN scale into W -> bf16 in STAGING-COALESCED layout Wt.
__global__ __launch_bounds__(256) void prep_w(
    const float* __restrict__ phi_w, const float* __restrict__ phi_g, const float* __restrict__ phi_b,
    const float* __restrict__ phi_m, const float* __restrict__ phi_v,
    const float* __restrict__ th_w, const float* __restrict__ th_g, const float* __restrict__ th_b,
    const float* __restrict__ th_m, const float* __restrict__ th_v,
    const float* __restrict__ ro_w, const float* __restrict__ ro_g, const float* __restrict__ ro_b,
    const float* __restrict__ ro_m, const float* __restrict__ ro_v,
    const float* __restrict__ va_w, const float* __restrict__ va_g, const float* __restrict__ va_b,
    const float* __restrict__ va_m, const float* __restrict__ va_v,
    ushort_t* __restrict__ Wt, float* __restrict__ be)
{
    const int o = blockIdx.x;  // 0..831
    const int t = threadIdx.x; // = c
    const float *src, *g, *bb, *mm, *vv; int orel;
    if (o < 64)       { src = phi_w; g = phi_g; bb = phi_b; mm = phi_m; vv = phi_v; orel = o; }
    else if (o < 320) { src = th_w;  g = th_g;  bb = th_b;  mm = th_m;  vv = th_v;  orel = o - 64; }
    else if (o < 576) { src = ro_w;  g = ro_g;  bb = ro_b;  mm = ro_m;  vv = ro_v;  orel = o - 320; }
    else              { src = va_w;  g = va_g;  bb = va_b;  mm = va_m;  vv = va_v;  orel = o - 576; }
    const float s = g[orel] / sqrtf(vv[orel] + 1e-5f);
    const int ot = o >> 6, os = (o >> 4) & 3, st = t >> 5;
    const size_t flat = ((((size_t)ot * 8 + st) * 4 + os) * 64 + ((t >> 3) & 3) * 16 + (o & 15)) * 8 + (t & 7);
    Wt[flat] = f2bf(src[orel * C_ + t] * s);
    if (t == 0) be[o] = bb[orel] - mm[orel] * s;
}

// ---------------- X[b][c][n] fp32 -> Xs bf16 in STAGING-COALESCED layout
__global__ __launch_bounds__(256) void xpose(
    const float* __restrict__ X, ushort_t* __restrict__ Xs)
{
    __shared__ float T[64][65];
    const int b = blockIdx.z, c0 = blockIdx.y * 64, n0 = blockIdx.x * 64;
    const int t = threadIdx.x;
#pragma unroll
    for (int p = 0; p < 4; ++p) {
        int c = p * 16 + (t >> 4), nn = (t & 15) * 4;
        float4 v = *(const float4*)&X[((size_t)b * C_ + c0 + c) * N_ + n0 + nn];
        T[c][nn] = v.x; T[c][nn + 1] = v.y; T[c][nn + 2] = v.z; T[c][nn + 3] = v.w;
    }
    __syncthreads();
#pragma unroll
    for (int p = 0; p < 4; ++p) {
        int nn = p * 16 + (t >> 4), cl = (t & 15) * 4;
        uint2 uu;
        uu.x = cvtpk(T[cl][nn], T[cl + 1][nn]);
        uu.y = cvtpk(T[cl + 2][nn], T[cl + 3][nn]);
        const int n = n0 + nn, c = c0 + cl;
        const int nt = n >> 8, nr = n & 255;
        const int st = c >> 5, g8 = (c >> 3) & 3, e = c & 7;  // e in {0,4}
        const size_t base = ((((size_t)b * 36 + nt) * 8 + st) * 1024
                             + (nr >> 4) * 64 + g8 * 16 + (nr & 15)) * 8 + e;
        *(uint2*)&Xs[base] = uu;
    }
}

// ---------------- fused bf16-MFMA projection (validated R12/R14 shape, FROZEN)
__global__ __launch_bounds__(256) void proj_mfma_all(
    const ushort_t* __restrict__ Wt, const float* __restrict__ be,
    const ushort_t* __restrict__ Xs,
    ushort_t* __restrict__ Pbf, ushort_t* __restrict__ Tbf,
    ushort_t* __restrict__ Vbf, ushort_t* __restrict__ Rt)
{
    __shared__ short sm[9216];  // 18 KB: epilogue transpose tiles only
    const int t = threadIdx.x;
    const int l = t & 63, w = t >> 6;
    const int idx = blockIdx.x;          // 0..3743
    const int xcd = idx & 7, pos = idx >> 3;
    const int vid = xcd * 468 + pos;     // 468 = 36*13 blocks per XCD chunk
    const int ot  = vid % 13;
    const int r   = vid / 13;            // 0..287
    const int b   = r / 36;
    const int nt  = r % 36;
    const int n0  = nt * 256;
    const int o0  = ot * 64;

    const bf16x8* Wv = (const bf16x8*)Wt;
    const bf16x8* Xf = (const bf16x8*)Xs;
    const size_t xbase = ((size_t)b * 36 + nt) * 8192;  // 8 stages x 1024 cells
    const size_t wbase = (size_t)ot * 2048;             // 8 stages x 256 cells
    const int boff = (l >> 4) * 16 + (l & 15);          // == l (coalesced)

    f32x4 zr = {0.f, 0.f, 0.f, 0.f};
    f32x4 acc[4][4];
#pragma unroll
    for (int i = 0; i < 4; ++i)
#pragma unroll
        for (int j = 0; j < 4; ++j) acc[i][j] = zr;

    // prologue: stage-0 fragments
    bf16x8 A0[4], B0[4];
#pragma unroll
    for (int os = 0; os < 4; ++os) A0[os] = Wv[wbase + os * 64 + l];
#pragma unroll
    for (int j = 0; j < 4; ++j)   B0[j]  = Xf[xbase + (w * 4 + j) * 64 + boff];

#pragma unroll
    for (int st = 0; st < 8; ++st) {
        bf16x8 A1[4], B1[4];
        if (st < 7) {  // prefetch next stage (hides L2 latency under MFMA)
#pragma unroll
            for (int os = 0; os < 4; ++os)
                A1[os] = Wv[wbase + (st + 1) * 256 + os * 64 + l];
#pragma unroll
            for (int j = 0; j < 4; ++j)
                B1[j] = Xf[xbase + (size_t)(st + 1) * 1024 + (w * 4 + j) * 64 + boff];
        }
#pragma unroll
        for (int os = 0; os < 4; ++os)
#pragma unroll
            for (int j = 0; j < 4; ++j)
                acc[os][j] = __builtin_amdgcn_mfma_f32_16x16x32_bf16(A0[os], B0[j], acc[os][j], 0, 0, 0);
#pragma unroll
        for (int os = 0; os < 4; ++os) A0[os] = A1[os];
#pragma unroll
        for (int j = 0; j < 4; ++j)   B0[j]  = B1[j];
    }

    // epilogue (block-uniform branch on o0); LDS 18KB; cvt_pk bf16 converts
    if (o0 >= 320 && o0 < 576) {
        const int od = o0 - 320;
        ushort_t* Tt = (ushort_t*)sm + w * (32 * 72);
#pragma unroll
        for (int half = 0; half < 2; ++half) {
            __syncthreads();
#pragma unroll
            for (int jj = 0; jj < 2; ++jj) {
                const int j = half * 2 + jj;
                const int row = jj * 16 + (l & 15);
#pragma unroll
                for (int os = 0; os < 4; ++os) {
                    const int scol0 = os * 16 + (l >> 4) * 4;  // multiple of 4
                    const float b0 = be[o0 + scol0], b1 = be[o0 + scol0 + 1];
                    const float b2 = be[o0 + scol0 + 2], b3 = be[o0 + scol0 + 3];
                    unsigned int p0 = cvtpk(fmaxf(acc[os][j][0] + b0, 0.f),
                                            fmaxf(acc[os][j][1] + b1, 0.f));
                    unsigned int p1 = cvtpk(fmaxf(acc[os][j][2] + b2, 0.f),
                                            fmaxf(acc[os][j][3] + b3, 0.f));
                    *(unsigned int*)&Tt[row * 72 + scol0]     = p0;
                    *(unsigned int*)&Tt[row * 72 + scol0 + 2] = p1;
                }
            }
            __syncthreads();
#pragma unroll
            for (int p = 0; p < 4; ++p) {
                const int lrow = p * 8 + (l >> 3);
                uint4 v = *(const uint4*)&Tt[lrow * 72 + (l & 7) * 8];
                *(uint4*)&Rt[((size_t)b * N_ + n0 + w * 64 + half * 32 + lrow) * 256 + od + (l & 7) * 8] = v;
            }
        }
    } else {
        ushort_t* dst; int od, osz;
        if (o0 < 64)       { dst = Pbf; od = o0;       osz = 64;  }
        else if (o0 < 320) { dst = Tbf; od = o0 - 64;  osz = 256; }
        else               { dst = Vbf; od = o0 - 576; osz = 256; }
        ushort_t* Tw = (ushort_t*)sm + w * (32 * 68);
        const int c = l & 15;
#pragma unroll
        for (int half = 0; half < 2; ++half) {
            __syncthreads();
#pragma unroll
            for (int osl = 0; osl < 2; ++osl) {
                const int os = half * 2 + osl;
#pragma unroll
                for (int r2 = 0; r2 < 4; ++r2) {
                    const int lrow = osl * 16 + (l >> 4) * 4 + r2;
                    const int orow = half * 32 + lrow;
                    const float bias = be[o0 + orow];
                    unsigned int p0 = cvtpk(fmaxf(acc[os][0][r2] + bias, 0.f),
                                            fmaxf(acc[os][1][r2] + bias, 0.f));
                    unsigned int p1 = cvtpk(fmaxf(acc[os][2][r2] + bias, 0.f),
                                            fmaxf(acc[os][3][r2] + bias, 0.f));
                    Tw[lrow * 68 + c]      = (ushort_t)p0;
                    Tw[lrow * 68 + 16 + c] = (ushort_t)(p0 >> 16);
                    Tw[lrow * 68 + 32 + c] = (ushort_t)p1;
                    Tw[lrow * 68 + 48 + c] = (ushort_t)(p1 >> 16);
                }
            }
            __syncthreads();
#pragma unroll
            for (int i = 0; i < 8; ++i) {
                const int lrow = i * 4 + (l >> 4);
                ushort4 v = *(const ushort4*)&Tw[lrow * 68 + (l & 15) * 4];
                *(ushort4*)&dst[((size_t)(b * osz + od + half * 32 + lrow)) * N_ + n0 + w * 64 + (l & 15) * 4] = v;
            }
        }
    }
}

// ---------------- theta row stats: st2[row] = (max, 1/sum(exp(x-max))) over N
__global__ __launch_bounds__(256) void rowstat_n(
    const ushort_t* __restrict__ T, float* __restrict__ st2)
{
    const int row = blockIdx.x;  // b*256 + s
    const ushort4* p = (const ushort4*)(T + (size_t)row * N_);
    const int t = threadIdx.x;
    float v[36];
    float mx = -INFINITY;
#pragma unroll
    for (int i = 0; i < 9; ++i) {
        ushort4 u = p[t + i * 256];
        v[i * 4 + 0] = bf2f(u.x); v[i * 4 + 1] = bf2f(u.y);
        v[i * 4 + 2] = bf2f(u.z); v[i * 4 + 3] = bf2f(u.w);
        mx = fmaxf(mx, fmaxf(fmaxf(v[i * 4], v[i * 4 + 1]), fmaxf(v[i * 4 + 2], v[i * 4 + 3])));
    }
    __shared__ float red[256];
    red[t] = mx; __syncthreads();
    for (int s2 = 128; s2 > 0; s2 >>= 1) {
        if (t < s2) red[t] = fmaxf(red[t], red[t + s2]);
        __syncthreads();
    }
    mx = red[0]; __syncthreads();
    float sum = 0.f;
#pragma unroll
    for (int i = 0; i < 36; ++i) sum += __expf(v[i] - mx);
    red[t] = sum; __syncthreads();
    for (int s2 = 128; s2 > 0; s2 >>= 1) {
        if (t < s2) red[t] += red[t + s2];
        __syncthreads();
    }
    if (t == 0) ((float2*)st2)[row] = make_float2(mx, 1.0f / red[0]);
}

// ---------------- per-n stats over raw Rt rows (256 bf16): parallel standalone kernel
// (R15 post-mortem: fusing this into qt_mfma serialized 64 dependent shfl-chains/wave
//  and cost +50us. Standalone: 2304 blocks, full BW, ~7us.)
__global__ __launch_bounds__(256) void rowstat_rt(
    const ushort_t* __restrict__ R, float* __restrict__ st2r)
{
    const int w = threadIdx.x >> 6, l = threadIdx.x & 63;
    const size_t row0 = (size_t)blockIdx.x * 32 + w * 8;
    for (int r = 0; r < 8; ++r) {
        const ushort4* p = (const ushort4*)(R + (row0 + r) * 256);
        ushort4 u = p[l];
        float f0 = bf2f(u.x), f1 = bf2f(u.y), f2 = bf2f(u.z), f3 = bf2f(u.w);
        float mx = fmaxf(fmaxf(f0, f1), fmaxf(f2, f3));
#pragma unroll
        for (int m = 1; m < 64; m <<= 1) mx = fmaxf(mx, __shfl_xor(mx, m));
        float s = __expf(f0 - mx) + __expf(f1 - mx) + __expf(f2 - mx) + __expf(f3 - mx);
#pragma unroll
        for (int m = 1; m < 64; m <<= 1) s += __shfl_xor(s, m);
        if (l == 0) ((float2*)st2r)[row0 + r] = make_float2(mx, 1.0f / s);
    }
}

// ---------------- MFMA: P[chunk][b][k][s] = sum_{n in chunk} A[b,k,n] * w(Bm)[b,s,n]
// obf16: write partials as bf16 (discrib path; positive summands, error crushed by softmax)
__global__ __launch_bounds__(256) void ks_mfma(
    const ushort_t* __restrict__ A, const ushort_t* __restrict__ Bm,
    const float* __restrict__ st2, float* __restrict__ P, int obf16)
{
    __shared__ short sm[32768];
    const int t = threadIdx.x;
    const int l = t & 63, w = t >> 6;
    const int chunk = blockIdx.x, b = blockIdx.y;
    const int ccell = chunk * 32;

    const uint4* Av = (const uint4*)A;
    const uint4* Bv = (const uint4*)Bm;
    const float2* S2 = (const float2*)st2;
    uint4* smv = (uint4*)sm;
    const bool doexp = (st2 != nullptr);

    uint4 wreg[8], xreg[8];
    float2 sreg[8];
#pragma unroll
    for (int i = 0; i < 8; ++i) {
        int cell = i * 256 + t;
        int osub = cell >> 9, g = (cell >> 4) & 31, oi = cell & 15;
        wreg[i] = Av[(size_t)(b * 64 + osub * 16 + oi) * NC8 + ccell + g];
    }
#pragma unroll
    for (int i = 0; i < 8; ++i) {
        int cell = i * 256 + t;
        int s = cell >> 7, g8 = (cell >> 4) & 7, ni = cell & 15;
        int row = s * 16 + ni;
        xreg[i] = Bv[(size_t)(b * 256 + row) * NC8 + ccell + g8];
        if (doexp) sreg[i] = S2[b * 256 + row];
    }
#pragma unroll
    for (int i = 0; i < 8; ++i) smv[i * 256 + t] = wreg[i];
#pragma unroll
    for (int i = 0; i < 8; ++i) smv[2048 + i * 256 + t] = doexp ? expcell(xreg[i], sreg[i]) : xreg[i];
    __syncthreads();

    f32x4 zr = {0.f, 0.f, 0.f, 0.f};
    f32x4 acc[4][4];
#pragma unroll
    for (int i = 0; i < 4; ++i)
#pragma unroll
        for (int j = 0; j < 4; ++j) acc[i][j] = zr;

    const bf16x8* smW = (const bf16x8*)sm;
    const bf16x8* smX = (const bf16x8*)(sm + 16384);

    for (int st = 0; st < 4; ++st) {
        if (st < 3) {
#pragma unroll
            for (int i = 0; i < 8; ++i) {
                int cell = i * 256 + t;
                int s = cell >> 7, g8 = (cell >> 4) & 7, ni = cell & 15;
                int row = s * 16 + ni;
                xreg[i] = Bv[(size_t)(b * 256 + row) * NC8 + ccell + (st + 1) * 8 + g8];
            }
        }
#pragma unroll
        for (int kgl = 0; kgl < 2; ++kgl) {
            const int kg = st * 2 + kgl;
            bf16x8 Af[4], Bf[4];
#pragma unroll
            for (int os = 0; os < 4; ++os)
                Af[os] = smW[(os * 32 + kg * 4 + (l >> 4)) * 16 + (l & 15)];
#pragma unroll
            for (int j = 0; j < 4; ++j)
                Bf[j] = smX[((w * 4 + j) * 8 + kgl * 4 + (l >> 4)) * 16 + (l & 15)];
#pragma unroll
            for (int os = 0; os < 4; ++os)
#pragma unroll
                for (int j = 0; j < 4; ++j)
                    acc[os][j] = __builtin_amdgcn_mfma_f32_16x16x32_bf16(Af[os], Bf[j], acc[os][j], 0, 0, 0);
        }
        __syncthreads();
        if (st < 3) {
#pragma unroll
            for (int i = 0; i < 8; ++i) smv[2048 + i * 256 + t] = doexp ? expcell(xreg[i], sreg[i]) : xreg[i];
            __syncthreads();
        }
    }

    if (obf16) {
        ushort_t* Pb = (ushort_t*)P + ((size_t)(chunk * B_ + b)) * TILE_KS;
#pragma unroll
        for (int os = 0; os < 4; ++os)
#pragma unroll
            for (int r = 0; r < 4; ++r) {
                const int k = os * 16 + (l >> 4) * 4 + r;
                unsigned int p0 = cvtpk(acc[os][0][r], acc[os][1][r]);
                unsigned int p1 = cvtpk(acc[os][2][r], acc[os][3][r]);
                Pb[k * 256 + w * 64 + 0  + (l & 15)] = (ushort_t)p0;
                Pb[k * 256 + w * 64 + 16 + (l & 15)] = (ushort_t)(p0 >> 16);
                Pb[k * 256 + w * 64 + 32 + (l & 15)] = (ushort_t)p1;
                Pb[k * 256 + w * 64 + 48 + (l & 15)] = (ushort_t)(p1 >> 16);
            }
    } else {
        float* Pb = P + ((size_t)(chunk * B_ + b)) * TILE_KS;
#pragma unroll
        for (int os = 0; os < 4; ++os)
#pragma unroll
            for (int r = 0; r < 4; ++r) {
                const int k = os * 16 + (l >> 4) * 4 + r;
#pragma unroll
                for (int j = 0; j < 4; ++j)
                    Pb[k * 256 + (w * 4 + j) * 16 + (l & 15)] = acc[os][j][r];
            }
    }
}

// ---------------- MFMA: Qraw[b][n][k](bf16) = sum_s Dbf[b,k,s] * softmax_s(Rt)[b,n,s]
// stats from global st2r (R12 validated form); fused nrm2 atomics; bf16 output.
__global__ __launch_bounds__(256) void qt_mfma(
    const ushort_t* __restrict__ Dbf,  // [b][64][256]
    const ushort_t* __restrict__ Rraw, // [b][N][256] raw rou
    const float* __restrict__ st2r,    // [b*N] (max, invsum)
    ushort_t* __restrict__ Qraw,       // [b][N][64] bf16
    float* __restrict__ Nrm)           // [b][64], pre-zeroed
{
    __shared__ short sm[32768];
    const int t = threadIdx.x;
    const int l = t & 63, w = t >> 6;
    const int b = blockIdx.x / 36;
    const int n0 = (blockIdx.x % 36) * 256;

    const uint4* Av = (const uint4*)Dbf;
    const uint4* Xv = (const uint4*)Rraw;
    const float2* S2 = (const float2*)st2r;
    uint4* smv = (uint4*)sm;

    uint4 wreg[8], xreg[8];
    float2 sreg[8];
#pragma unroll
    for (int i = 0; i < 8; ++i) {
        int cell = i * 256 + t;
        int osub = cell >> 9, g = (cell >> 4) & 31, oi = cell & 15;
        wreg[i] = Av[(size_t)(b * 64 + osub * 16 + oi) * 32 + g];
    }
#pragma unroll
    for (int i = 0; i < 8; ++i) {
        int cell = i * 256 + t;
        int s = cell >> 7, g8 = (cell >> 4) & 7, ni = cell & 15;
        xreg[i] = Xv[((size_t)b * N_ + n0 + s * 16 + ni) * 32 + g8];
        sreg[i] = S2[(size_t)b * N_ + n0 + s * 16 + ni];  // row stats constant across stages
    }
#pragma unroll
    for (int i = 0; i < 8; ++i) smv[i * 256 + t] = wreg[i];
#pragma unroll
    for (int i = 0; i < 8; ++i) smv[2048 + i * 256 + t] = expcell(xreg[i], sreg[i]);
    __syncthreads();

    f32x4 zr = {0.f, 0.f, 0.f, 0.f};
    f32x4 acc[4][4];
#pragma unroll
    for (int i = 0; i < 4; ++i)
#pragma unroll
        for (int j = 0; j < 4; ++j) acc[i][j] = zr;

    const bf16x8* smW = (const bf16x8*)sm;
    const bf16x8* smX = (const bf16x8*)(sm + 16384);

    for (int st = 0; st < 4; ++st) {
        if (st < 3) {
#pragma unroll
            for (int i = 0; i < 8; ++i) {
                int cell = i * 256 + t;
                int s = cell >> 7, g8 = (cell >> 4) & 7, ni = cell & 15;
                xreg[i] = Xv[((size_t)b * N_ + n0 + s * 16 + ni) * 32 + (st + 1) * 8 + g8];
            }
        }
#pragma unroll
        for (int kgl = 0; kgl < 2; ++kgl) {
            const int kg = st * 2 + kgl;
            bf16x8 Af[4], Bf[4];
#pragma unroll
            for (int os = 0; os < 4; ++os)
                Af[os] = smW[(os * 32 + kg * 4 + (l >> 4)) * 16 + (l & 15)];
#pragma unroll
            for (int j = 0; j < 4; ++j)
                Bf[j] = smX[((w * 4 + j) * 8 + kgl * 4 + (l >> 4)) * 16 + (l & 15)];
#pragma unroll
            for (int os = 0; os < 4; ++os)
#pragma unroll
                for (int j = 0; j < 4; ++j)
                    acc[os][j] = __builtin_amdgcn_mfma_f32_16x16x32_bf16(Af[os], Bf[j], acc[os][j], 0, 0, 0);
        }
        __syncthreads();
        if (st < 3) {
#pragma unroll
            for (int i = 0; i < 8; ++i) smv[2048 + i * 256 + t] = expcell(xreg[i], sreg[i]);
            __syncthreads();
        }
    }

    // epilogue: nrm2 partials + [n][k] transposed bf16 stores
    float* snrm = (float*)sm + 9216;
    __syncthreads();
    if (t < 64) snrm[t] = 0.f;
    __syncthreads();
#pragma unroll
    for (int os = 0; os < 4; ++os)
#pragma unroll
        for (int r = 0; r < 4; ++r) {
            float p = 0.f;
#pragma unroll
            for (int j = 0; j < 4; ++j) p = fmaf(acc[os][j][r], acc[os][j][r], p);
#pragma unroll
            for (int m = 1; m < 16; m <<= 1) p += __shfl_xor(p, m);
            if ((l & 15) == 0) atomicAdd(&snrm[os * 16 + (l >> 4) * 4 + r], p);
        }
    float* Tw = (float*)sm + w * 2304;  // per-wave [32][72]
#pragma unroll
    for (int h = 0; h < 2; ++h) {
        __syncthreads();
#pragma unroll
        for (int os = 0; os < 4; ++os)
#pragma unroll
            for (int r = 0; r < 4; ++r) {
                const int kcol = os * 16 + (l >> 4) * 4 + r;
#pragma unroll
                for (int jj = 0; jj < 2; ++jj)
                    Tw[(jj * 16 + (l & 15)) * 72 + kcol] = acc[os][h * 2 + jj][r];
            }
        __syncthreads();
#pragma unroll
        for (int i = 0; i < 8; ++i) {
            const int lrow = i * 4 + (l >> 4);
            f32x4 v = *(const f32x4*)&Tw[lrow * 72 + (l & 15) * 4];
            uint2 uu;
            uu.x = cvtpk(v[0], v[1]);
            uu.y = cvtpk(v[2], v[3]);
            *(uint2*)&Qraw[((size_t)b * N_ + n0 + w * 64 + h * 32 + lrow) * 64 + (l & 15) * 4] = uu;
        }
    }
    __syncthreads();
    if (t < 64) atomicAdd(&Nrm[b * 64 + t], snrm[t]);
}

// ---------------- partial-sum reductions over NCHUNK
__global__ __launch_bounds__(256) void chunk_reduce_bf(
    const ushort_t* __restrict__ P, ushort_t* __restrict__ outb)
{
    const int i2 = blockIdx.x * 256 + threadIdx.x;  // uint2 cell = 4 bf16
    float s0 = 0.f, s1 = 0.f, s2 = 0.f, s3 = 0.f;
#pragma unroll
    for (int c = 0; c < NCHUNK; ++c) {
        uint2 u = ((const uint2*)P)[(size_t)c * (B_ * TILE_KS / 4) + i2];
        s0 += bf2f((ushort_t)u.x); s1 += bf2f(u.x >> 16);
        s2 += bf2f((ushort_t)u.y); s3 += bf2f(u.y >> 16);
    }
    uint2 o;
    o.x = cvtpk(s0, s1);
    o.y = cvtpk(s2, s3);
    ((uint2*)outb)[i2] = o;
}
__global__ __launch_bounds__(256) void chunk_reduce_f(
    const float* __restrict__ P, float* __restrict__ outf)
{
    const int i4 = blockIdx.x * 256 + threadIdx.x;
    float4 s = make_float4(0.f, 0.f, 0.f, 0.f);
#pragma unroll
    for (int c = 0; c < NCHUNK; ++c) {
        float4 v = ((const float4*)P)[(size_t)c * (B_ * TILE_KS / 4) + i4];
        s.x += v.x; s.y += v.y; s.z += v.z; s.w += v.w;
    }
    ((float4*)outf)[i4] = s;
}

// ---------------- Q = softmax_k(Qraw * invn); write Qout[b][n][k] fp32 + Qbf[b][k][n] bf16
__global__ __launch_bounds__(256) void q_final(
    const ushort_t* __restrict__ Qraw, const float* __restrict__ Nrm,
    float* __restrict__ Qout, ushort_t* __restrict__ Qbf)
{
    __shared__ ushort_t Tq[64 * 256];
    __shared__ float invn[64];
    const int b = blockIdx.y;
    const int n0 = blockIdx.x * 256;
    const int t = threadIdx.x;
    const int l = t & 63, w = t >> 6;
    if (t < 64) invn[t] = 1.0f / fmaxf(sqrtf(Nrm[b * 64 + t]), 1e-12f);
    __syncthreads();
    const uint4* q4 = (const uint4*)(Qraw + ((size_t)b * N_ + n0 + t) * 64);
    float q[64];
#pragma unroll
    for (int kk = 0; kk < 8; ++kk) {
        uint4 u = q4[kk];
        q[kk * 8 + 0] = bf2f((ushort_t)u.x); q[kk * 8 + 1] = bf2f(u.x >> 16);
        q[kk * 8 + 2] = bf2f((ushort_t)u.y); q[kk * 8 + 3] = bf2f(u.y >> 16);
        q[kk * 8 + 4] = bf2f((ushort_t)u.z); q[kk * 8 + 5] = bf2f(u.z >> 16);
        q[kk * 8 + 6] = bf2f((ushort_t)u.w); q[kk * 8 + 7] = bf2f(u.w >> 16);
    }
    float mx = -INFINITY;
#pragma unroll
    for (int k = 0; k < 64; ++k) { q[k] *= invn[k]; mx = fmaxf(mx, q[k]); }
    float sum = 0.f;
#pragma unroll
    for (int k = 0; k < 64; ++k) { q[k] = __expf(q[k] - mx); sum += q[k]; }
    const float inv = 1.0f / sum;
    const size_t base = ((size_t)b * N_ + n0 + t) * 64;
#pragma unroll
    for (int kk = 0; kk < 16; ++kk) {
        f32x4 v = {q[kk * 4] * inv, q[kk * 4 + 1] * inv, q[kk * 4 + 2] * inv, q[kk * 4 + 3] * inv};
        *(f32x4*)&Qout[base + kk * 4] = v;
        q[kk * 4] = v[0]; q[kk * 4 + 1] = v[1]; q[kk * 4 + 2] = v[2]; q[kk * 4 + 3] = v[3];
    }
#pragma unroll
    for (int k = 0; k < 64; ++k) Tq[k * 256 + t] = f2bf(q[k]);
    __syncthreads();
#pragma unroll
    for (int kk = 0; kk < 16; ++kk) {
        const int k = kk * 4 + w;
        ushort4 v = *(const ushort4*)&Tq[k * 256 + l * 4];
        *(ushort4*)&Qbf[((size_t)b * 64 + k) * N_ + n0 + l * 4] = v;
    }
}

// ---------------- Z[b,s,k] = ZnT[b,k,s] / l2norm over s (qsum cancels in l2norm)
__global__ __launch_bounds__(256) void z_final(
    const float* __restrict__ ZnT, float* __restrict__ Z)
{
    __shared__ float red[256];
    __shared__ float invn[64];
    const int b = blockIdx.x;
    const int t = threadIdx.x;
    const float* Zb = ZnT + (size_t)b * TILE_KS;
    {
        const int k = t >> 2, qq = t & 3;
        float ss = 0.f;
        for (int j = 0; j < 64; ++j) {
            float v = Zb[k * 256 + qq * 64 + j];
            ss = fmaf(v, v, ss);
        }
        red[t] = ss;
    }
    __syncthreads();
    if ((t & 3) == 0) {
        float tot = red[t] + red[t + 1] + red[t + 2] + red[t + 3];
        invn[t >> 2] = 1.0f / fmaxf(sqrtf(tot), 1e-12f);
    }
    __syncthreads();
    {
        const int k = t & 63, w = t >> 6;
        const float sc = invn[k];
        for (int j = 0; j < 64; ++j) {
            int s = w * 64 + j;
            Z[((size_t)b * 256 + s) * 64 + k] = Zb[k * 256 + s] * sc;
        }
    }
}

extern "C" void kernel_launch(void* const* d_in, const int* in_sizes, int n_in,
                              void* d_out, int out_size, void* d_ws, size_t ws_size,
                              hipStream_t stream)
{
    const float* X       = (const float*)d_in[0];
    const float* phi_w   = (const float*)d_in[1];
    const float* phi_g   = (const float*)d_in[2];
    const float* phi_b   = (const float*)d_in[3];
    const float* phi_m   = (const float*)d_in[4];
    const float* phi_v   = (const float*)d_in[5];
    const float* theta_w = (const float*)d_in[6];
    const float* theta_g = (const float*)d_in[7];
    const float* theta_b = (const float*)d_in[8];
    const float* theta_m = (const float*)d_in[9];
    const float* theta_v = (const float*)d_in[10];
    const float* rou_w   = (const float*)d_in[11];
    const float* rou_g   = (const float*)d_in[12];
    const float* rou_b   = (const float*)d_in[13];
    const float* rou_m   = (const float*)d_in[14];
    const float* rou_v   = (const float*)d_in[15];
    const float* val_w   = (const float*)d_in[16];
    const float* val_g   = (const float*)d_in[17];
    const float* val_b   = (const float*)d_in[18];
    const float* val_m   = (const float*)d_in[19];
    const float* val_v   = (const float*)d_in[20];

    float* ws = (float*)d_ws;
    size_t off = 0;
    ushort_t* Xs  = (ushort_t*)(ws + off); off += (size_t)B_ * N_ * C_ / 2;
    ushort_t* Wt  = (ushort_t*)(ws + off); off += 832 * C_ / 2;
    float* be     = ws + off; off += 832;
    float* st2    = ws + off; off += 2 * B_ * 256;
    float* st2r   = ws + off; off += 2 * B_ * N_;
    ushort_t* Pbf = (ushort_t*)(ws + off); off += (size_t)B_ * 64 * N_ / 2;
    ushort_t* Tbf = (ushort_t*)(ws + off); off += (size_t)B_ * 256 * N_ / 2;
    ushort_t* Vbf = (ushort_t*)(ws + off); off += (size_t)B_ * 256 * N_ / 2;
    ushort_t* Rt  = (ushort_t*)(ws + off); off += (size_t)B_ * N_ * 256 / 2;
    ushort_t* Qbf = (ushort_t*)(ws + off); off += (size_t)B_ * 64 * N_ / 2;
    ushort_t* Dbf = (ushort_t*)(ws + off); off += (size_t)B_ * 64 * 256 / 2;
    float* part   = ws + off; off += (size_t)NCHUNK * B_ * TILE_KS;
    ushort_t* Qraw = (ushort_t*)(ws + off); off += (size_t)B_ * N_ * 64 / 2;
    float* ZnT    = ws + off; off += (size_t)B_ * TILE_KS;
    float* Nrm    = ws + off; off += B_ * 64;

    float* Zout = (float*)d_out;                  // B*S*K
    float* Qout = Zout + (size_t)B_ * S_ * K_;    // B*N*K

    hipMemsetAsync(Nrm, 0, B_ * 64 * sizeof(float), stream);

    prep_w<<<832, 256, 0, stream>>>(phi_w, phi_g, phi_b, phi_m, phi_v,
                                    theta_w, theta_g, theta_b, theta_m, theta_v,
                                    rou_w, rou_g, rou_b, rou_m, rou_v,
                                    val_w, val_g, val_b, val_m, val_v, Wt, be);
    xpose<<<dim3(N_ / 64, C_ / 64, B_), 256, 0, stream>>>(X, Xs);

    proj_mfma_all<<<3744, 256, 0, stream>>>(Wt, be, Xs, Pbf, Tbf, Vbf, Rt);

    rowstat_n<<<B_ * 256, 256, 0, stream>>>(Tbf, st2);
    rowstat_rt<<<B_ * N_ / 32, 256, 0, stream>>>(Rt, st2r);

    ks_mfma<<<dim3(NCHUNK, B_), 256, 0, stream>>>(Pbf, Tbf, st2, part, 1);
    chunk_reduce_bf<<<B_ * TILE_KS / 1024, 256, 0, stream>>>((const ushort_t*)part, Dbf);

    qt_mfma<<<36 * B_, 256, 0, stream>>>(Dbf, Rt, st2r, Qraw, Nrm);
    q_final<<<dim3(36, B_), 256, 0, stream>>>(Qraw, Nrm, Qout, Qbf);

    ks_mfma<<<dim3(NCHUNK, B_), 256, 0, stream>>>(Qbf, Vbf, (const float*)nullptr, part, 0);
    chunk_reduce_f<<<B_ * TILE_KS / 1024, 256, 0, stream>>>(part, ZnT);
    z_final<<<B_, 256, 0, stream>>>(ZnT, Zout);
}

// Round 17
// 193.899 us; speedup vs baseline: 1.2008x; 1.0146x over previous
//
#include <hip/hip_runtime.h>
#include <math.h>

#define B_ 8
#define C_ 256
#define N_ 9216
#define S_ 256
#define K_ 64
#define NCHUNK 36            // 9216 / 256
#define TILE_KS (K_ * S_)    // 16384
#define NC8 (N_ / 8)         // 1152 16B-cells per [*][N] bf16 row

typedef unsigned short ushort_t;
typedef __attribute__((ext_vector_type(8))) short bf16x8;
typedef __attribute__((ext_vector_type(4))) float f32x4;

static __device__ inline ushort_t f2bf(float x) {
    unsigned int u = __float_as_uint(x);
    unsigned int r = (u + 0x7fffu + ((u >> 16) & 1u)) >> 16;
    return (ushort_t)r;
}
static __device__ inline float bf2f(ushort_t u) {
    return __uint_as_float(((unsigned int)u) << 16);
}
// packed bf16 convert (RNE, same as f2bf): lo -> bits[15:0], hi -> bits[31:16]
static __device__ inline unsigned int cvtpk(float lo, float hi) {
    unsigned int r;
    asm("v_cvt_pk_bf16_f32 %0, %1, %2" : "=v"(r) : "v"(lo), "v"(hi));
    return r;
}

// exp-weight one 8-bf16 cell (row-constant max/invsum in s)
static __device__ inline uint4 expcell(uint4 u, float2 s) {
    uint4 r;
    unsigned int* up = (unsigned int*)&u;
    unsigned int* rp = (unsigned int*)&r;
#pragma unroll
    for (int q = 0; q < 4; ++q) {
        unsigned int x = up[q];
        float lo = __uint_as_float((x & 0xffffu) << 16);
        float hi = __uint_as_float(x & 0xffff0000u);
        rp[q] = cvtpk(__expf(lo - s.x) * s.y, __expf(hi - s.x) * s.y);
    }
    return r;
}

// ---------------- fold BN scale into W -> bf16 in STAGING-COALESCED layout Wt.
__global__ __launch_bounds__(256) void prep_w(
    const float* __restrict__ phi_w, const float* __restrict__ phi_g, const float* __restrict__ phi_b,
    const float* __restrict__ phi_m, const float* __restrict__ phi_v,
    const float* __restrict__ th_w, const float* __restrict__ th_g, const float* __restrict__ th_b,
    const float* __restrict__ th_m, const float* __restrict__ th_v,
    const float* __restrict__ ro_w, const float* __restrict__ ro_g, const float* __restrict__ ro_b,
    const float* __restrict__ ro_m, const float* __restrict__ ro_v,
    const float* __restrict__ va_w, const float* __restrict__ va_g, const float* __restrict__ va_b,
    const float* __restrict__ va_m, const float* __restrict__ va_v,
    ushort_t* __restrict__ Wt, float* __restrict__ be)
{
    const int o = blockIdx.x;  // 0..831
    const int t = threadIdx.x; // = c
    const float *src, *g, *bb, *mm, *vv; int orel;
    if (o < 64)       { src = phi_w; g = phi_g; bb = phi_b; mm = phi_m; vv = phi_v; orel = o; }
    else if (o < 320) { src = th_w;  g = th_g;  bb = th_b;  mm = th_m;  vv = th_v;  orel = o - 64; }
    else if (o < 576) { src = ro_w;  g = ro_g;  bb = ro_b;  mm = ro_m;  vv = ro_v;  orel = o - 320; }
    else              { src = va_w;  g = va_g;  bb = va_b;  mm = va_m;  vv = va_v;  orel = o - 576; }
    const float s = g[orel] / sqrtf(vv[orel] + 1e-5f);
    const int ot = o >> 6, os = (o >> 4) & 3, st = t >> 5;
    const size_t flat = ((((size_t)ot * 8 + st) * 4 + os) * 64 + ((t >> 3) & 3) * 16 + (o & 15)) * 8 + (t & 7);
    Wt[flat] = f2bf(src[orel * C_ + t] * s);
    if (t == 0) be[o] = bb[orel] - mm[orel] * s;
}

// ---------------- X[b][c][n] fp32 -> Xs bf16 in STAGING-COALESCED layout
__global__ __launch_bounds__(256) void xpose(
    const float* __restrict__ X, ushort_t* __restrict__ Xs)
{
    __shared__ float T[64][65];
    const int b = blockIdx.z, c0 = blockIdx.y * 64, n0 = blockIdx.x * 64;
    const int t = threadIdx.x;
#pragma unroll
    for (int p = 0; p < 4; ++p) {
        int c = p * 16 + (t >> 4), nn = (t & 15) * 4;
        float4 v = *(const float4*)&X[((size_t)b * C_ + c0 + c) * N_ + n0 + nn];
        T[c][nn] = v.x; T[c][nn + 1] = v.y; T[c][nn + 2] = v.z; T[c][nn + 3] = v.w;
    }
    __syncthreads();
#pragma unroll
    for (int p = 0; p < 4; ++p) {
        int nn = p * 16 + (t >> 4), cl = (t & 15) * 4;
        uint2 uu;
        uu.x = cvtpk(T[cl][nn], T[cl + 1][nn]);
        uu.y = cvtpk(T[cl + 2][nn], T[cl + 3][nn]);
        const int n = n0 + nn, c = c0 + cl;
        const int nt = n >> 8, nr = n & 255;
        const int st = c >> 5, g8 = (c >> 3) & 3, e = c & 7;  // e in {0,4}
        const size_t base = ((((size_t)b * 36 + nt) * 8 + st) * 1024
                             + (nr >> 4) * 64 + g8 * 16 + (nr & 15)) * 8 + e;
        *(uint2*)&Xs[base] = uu;
    }
}

// ---------------- fused bf16-MFMA projection (validated R12/R14 shape, FROZEN)
__global__ __launch_bounds__(256) void proj_mfma_all(
    const ushort_t* __restrict__ Wt, const float* __restrict__ be,
    const ushort_t* __restrict__ Xs,
    ushort_t* __restrict__ Pbf, ushort_t* __restrict__ Tbf,
    ushort_t* __restrict__ Vbf, ushort_t* __restrict__ Rt)
{
    __shared__ short sm[9216];  // 18 KB: epilogue transpose tiles only
    const int t = threadIdx.x;
    const int l = t & 63, w = t >> 6;
    const int idx = blockIdx.x;          // 0..3743
    const int xcd = idx & 7, pos = idx >> 3;
    const int vid = xcd * 468 + pos;     // 468 = 36*13 blocks per XCD chunk
    const int ot  = vid % 13;
    const int r   = vid / 13;            // 0..287
    const int b   = r / 36;
    const int nt  = r % 36;
    const int n0  = nt * 256;
    const int o0  = ot * 64;

    const bf16x8* Wv = (const bf16x8*)Wt;
    const bf16x8* Xf = (const bf16x8*)Xs;
    const size_t xbase = ((size_t)b * 36 + nt) * 8192;  // 8 stages x 1024 cells
    const size_t wbase = (size_t)ot * 2048;             // 8 stages x 256 cells
    const int boff = (l >> 4) * 16 + (l & 15);          // == l (coalesced)

    f32x4 zr = {0.f, 0.f, 0.f, 0.f};
    f32x4 acc[4][4];
#pragma unroll
    for (int i = 0; i < 4; ++i)
#pragma unroll
        for (int j = 0; j < 4; ++j) acc[i][j] = zr;

    // prologue: stage-0 fragments
    bf16x8 A0[4], B0[4];
#pragma unroll
    for (int os = 0; os < 4; ++os) A0[os] = Wv[wbase + os * 64 + l];
#pragma unroll
    for (int j = 0; j < 4; ++j)   B0[j]  = Xf[xbase + (w * 4 + j) * 64 + boff];

#pragma unroll
    for (int st = 0; st < 8; ++st) {
        bf16x8 A1[4], B1[4];
        if (st < 7) {  // prefetch next stage (hides L2 latency under MFMA)
#pragma unroll
            for (int os = 0; os < 4; ++os)
                A1[os] = Wv[wbase + (st + 1) * 256 + os * 64 + l];
#pragma unroll
            for (int j = 0; j < 4; ++j)
                B1[j] = Xf[xbase + (size_t)(st + 1) * 1024 + (w * 4 + j) * 64 + boff];
        }
#pragma unroll
        for (int os = 0; os < 4; ++os)
#pragma unroll
            for (int j = 0; j < 4; ++j)
                acc[os][j] = __builtin_amdgcn_mfma_f32_16x16x32_bf16(A0[os], B0[j], acc[os][j], 0, 0, 0);
#pragma unroll
        for (int os = 0; os < 4; ++os) A0[os] = A1[os];
#pragma unroll
        for (int j = 0; j < 4; ++j)   B0[j]  = B1[j];
    }

    // epilogue (block-uniform branch on o0); LDS 18KB; cvt_pk bf16 converts
    if (o0 >= 320 && o0 < 576) {
        const int od = o0 - 320;
        ushort_t* Tt = (ushort_t*)sm + w * (32 * 72);
#pragma unroll
        for (int half = 0; half < 2; ++half) {
            __syncthreads();
#pragma unroll
            for (int jj = 0; jj < 2; ++jj) {
                const int j = half * 2 + jj;
                const int row = jj * 16 + (l & 15);
#pragma unroll
                for (int os = 0; os < 4; ++os) {
                    const int scol0 = os * 16 + (l >> 4) * 4;  // multiple of 4
                    const float b0 = be[o0 + scol0], b1 = be[o0 + scol0 + 1];
                    const float b2 = be[o0 + scol0 + 2], b3 = be[o0 + scol0 + 3];
                    unsigned int p0 = cvtpk(fmaxf(acc[os][j][0] + b0, 0.f),
                                            fmaxf(acc[os][j][1] + b1, 0.f));
                    unsigned int p1 = cvtpk(fmaxf(acc[os][j][2] + b2, 0.f),
                                            fmaxf(acc[os][j][3] + b3, 0.f));
                    *(unsigned int*)&Tt[row * 72 + scol0]     = p0;
                    *(unsigned int*)&Tt[row * 72 + scol0 + 2] = p1;
                }
            }
            __syncthreads();
#pragma unroll
            for (int p = 0; p < 4; ++p) {
                const int lrow = p * 8 + (l >> 3);
                uint4 v = *(const uint4*)&Tt[lrow * 72 + (l & 7) * 8];
                *(uint4*)&Rt[((size_t)b * N_ + n0 + w * 64 + half * 32 + lrow) * 256 + od + (l & 7) * 8] = v;
            }
        }
    } else {
        ushort_t* dst; int od, osz;
        if (o0 < 64)       { dst = Pbf; od = o0;       osz = 64;  }
        else if (o0 < 320) { dst = Tbf; od = o0 - 64;  osz = 256; }
        else               { dst = Vbf; od = o0 - 576; osz = 256; }
        ushort_t* Tw = (ushort_t*)sm + w * (32 * 68);
        const int c = l & 15;
#pragma unroll
        for (int half = 0; half < 2; ++half) {
            __syncthreads();
#pragma unroll
            for (int osl = 0; osl < 2; ++osl) {
                const int os = half * 2 + osl;
#pragma unroll
                for (int r2 = 0; r2 < 4; ++r2) {
                    const int lrow = osl * 16 + (l >> 4) * 4 + r2;
                    const int orow = half * 32 + lrow;
                    const float bias = be[o0 + orow];
                    unsigned int p0 = cvtpk(fmaxf(acc[os][0][r2] + bias, 0.f),
                                            fmaxf(acc[os][1][r2] + bias, 0.f));
                    unsigned int p1 = cvtpk(fmaxf(acc[os][2][r2] + bias, 0.f),
                                            fmaxf(acc[os][3][r2] + bias, 0.f));
                    Tw[lrow * 68 + c]      = (ushort_t)p0;
                    Tw[lrow * 68 + 16 + c] = (ushort_t)(p0 >> 16);
                    Tw[lrow * 68 + 32 + c] = (ushort_t)p1;
                    Tw[lrow * 68 + 48 + c] = (ushort_t)(p1 >> 16);
                }
            }
            __syncthreads();
#pragma unroll
            for (int i = 0; i < 8; ++i) {
                const int lrow = i * 4 + (l >> 4);
                ushort4 v = *(const ushort4*)&Tw[lrow * 68 + (l & 15) * 4];
                *(ushort4*)&dst[((size_t)(b * osz + od + half * 32 + lrow)) * N_ + n0 + w * 64 + (l & 15) * 4] = v;
            }
        }
    }
}

// ---------------- theta row stats: st2[row] = (max, 1/sum(exp(x-max))) over N
__global__ __launch_bounds__(256) void rowstat_n(
    const ushort_t* __restrict__ T, float* __restrict__ st2)
{
    const int row = blockIdx.x;  // b*256 + s
    const ushort4* p = (const ushort4*)(T + (size_t)row * N_);
    const int t = threadIdx.x;
    float v[36];
    float mx = -INFINITY;
#pragma unroll
    for (int i = 0; i < 9; ++i) {
        ushort4 u = p[t + i * 256];
        v[i * 4 + 0] = bf2f(u.x); v[i * 4 + 1] = bf2f(u.y);
        v[i * 4 + 2] = bf2f(u.z); v[i * 4 + 3] = bf2f(u.w);
        mx = fmaxf(mx, fmaxf(fmaxf(v[i * 4], v[i * 4 + 1]), fmaxf(v[i * 4 + 2], v[i * 4 + 3])));
    }
    __shared__ float red[256];
    red[t] = mx; __syncthreads();
    for (int s2 = 128; s2 > 0; s2 >>= 1) {
        if (t < s2) red[t] = fmaxf(red[t], red[t + s2]);
        __syncthreads();
    }
    mx = red[0]; __syncthreads();
    float sum = 0.f;
#pragma unroll
    for (int i = 0; i < 36; ++i) sum += __expf(v[i] - mx);
    red[t] = sum; __syncthreads();
    for (int s2 = 128; s2 > 0; s2 >>= 1) {
        if (t < s2) red[t] += red[t + s2];
        __syncthreads();
    }
    if (t == 0) ((float2*)st2)[row] = make_float2(mx, 1.0f / red[0]);
}

// ---------------- per-n stats over raw Rt rows (256 bf16): parallel standalone kernel
__global__ __launch_bounds__(256) void rowstat_rt(
    const ushort_t* __restrict__ R, float* __restrict__ st2r)
{
    const int w = threadIdx.x >> 6, l = threadIdx.x & 63;
    const size_t row0 = (size_t)blockIdx.x * 32 + w * 8;
    for (int r = 0; r < 8; ++r) {
        const ushort4* p = (const ushort4*)(R + (row0 + r) * 256);
        ushort4 u = p[l];
        float f0 = bf2f(u.x), f1 = bf2f(u.y), f2 = bf2f(u.z), f3 = bf2f(u.w);
        float mx = fmaxf(fmaxf(f0, f1), fmaxf(f2, f3));
#pragma unroll
        for (int m = 1; m < 64; m <<= 1) mx = fmaxf(mx, __shfl_xor(mx, m));
        float s = __expf(f0 - mx) + __expf(f1 - mx) + __expf(f2 - mx) + __expf(f3 - mx);
#pragma unroll
        for (int m = 1; m < 64; m <<= 1) s += __shfl_xor(s, m);
        if (l == 0) ((float2*)st2r)[row0 + r] = make_float2(mx, 1.0f / s);
    }
}

// ---------------- MFMA: P[chunk][b][k][s] = sum_{n in chunk} A[b,k,n] * w(Bm)[b,s,n]
// obf16: write partials as bf16 (both discrib and znum paths; downstream contractions
// crush the 0.4% partial rounding)
__global__ __launch_bounds__(256) void ks_mfma(
    const ushort_t* __restrict__ A, const ushort_t* __restrict__ Bm,
    const float* __restrict__ st2, float* __restrict__ P, int obf16)
{
    __shared__ short sm[32768];
    const int t = threadIdx.x;
    const int l = t & 63, w = t >> 6;
    const int chunk = blockIdx.x, b = blockIdx.y;
    const int ccell = chunk * 32;

    const uint4* Av = (const uint4*)A;
    const uint4* Bv = (const uint4*)Bm;
    const float2* S2 = (const float2*)st2;
    uint4* smv = (uint4*)sm;
    const bool doexp = (st2 != nullptr);

    uint4 wreg[8], xreg[8];
    float2 sreg[8];
#pragma unroll
    for (int i = 0; i < 8; ++i) {
        int cell = i * 256 + t;
        int osub = cell >> 9, g = (cell >> 4) & 31, oi = cell & 15;
        wreg[i] = Av[(size_t)(b * 64 + osub * 16 + oi) * NC8 + ccell + g];
    }
#pragma unroll
    for (int i = 0; i < 8; ++i) {
        int cell = i * 256 + t;
        int s = cell >> 7, g8 = (cell >> 4) & 7, ni = cell & 15;
        int row = s * 16 + ni;
        xreg[i] = Bv[(size_t)(b * 256 + row) * NC8 + ccell + g8];
        if (doexp) sreg[i] = S2[b * 256 + row];
    }
#pragma unroll
    for (int i = 0; i < 8; ++i) smv[i * 256 + t] = wreg[i];
#pragma unroll
    for (int i = 0; i < 8; ++i) smv[2048 + i * 256 + t] = doexp ? expcell(xreg[i], sreg[i]) : xreg[i];
    __syncthreads();

    f32x4 zr = {0.f, 0.f, 0.f, 0.f};
    f32x4 acc[4][4];
#pragma unroll
    for (int i = 0; i < 4; ++i)
#pragma unroll
        for (int j = 0; j < 4; ++j) acc[i][j] = zr;

    const bf16x8* smW = (const bf16x8*)sm;
    const bf16x8* smX = (const bf16x8*)(sm + 16384);

    for (int st = 0; st < 4; ++st) {
        if (st < 3) {
#pragma unroll
            for (int i = 0; i < 8; ++i) {
                int cell = i * 256 + t;
                int s = cell >> 7, g8 = (cell >> 4) & 7, ni = cell & 15;
                int row = s * 16 + ni;
                xreg[i] = Bv[(size_t)(b * 256 + row) * NC8 + ccell + (st + 1) * 8 + g8];
            }
        }
#pragma unroll
        for (int kgl = 0; kgl < 2; ++kgl) {
            const int kg = st * 2 + kgl;
            bf16x8 Af[4], Bf[4];
#pragma unroll
            for (int os = 0; os < 4; ++os)
                Af[os] = smW[(os * 32 + kg * 4 + (l >> 4)) * 16 + (l & 15)];
#pragma unroll
            for (int j = 0; j < 4; ++j)
                Bf[j] = smX[((w * 4 + j) * 8 + kgl * 4 + (l >> 4)) * 16 + (l & 15)];
#pragma unroll
            for (int os = 0; os < 4; ++os)
#pragma unroll
                for (int j = 0; j < 4; ++j)
                    acc[os][j] = __builtin_amdgcn_mfma_f32_16x16x32_bf16(Af[os], Bf[j], acc[os][j], 0, 0, 0);
        }
        __syncthreads();
        if (st < 3) {
#pragma unroll
            for (int i = 0; i < 8; ++i) smv[2048 + i * 256 + t] = doexp ? expcell(xreg[i], sreg[i]) : xreg[i];
            __syncthreads();
        }
    }

    if (obf16) {
        ushort_t* Pb = (ushort_t*)P + ((size_t)(chunk * B_ + b)) * TILE_KS;
#pragma unroll
        for (int os = 0; os < 4; ++os)
#pragma unroll
            for (int r = 0; r < 4; ++r) {
                const int k = os * 16 + (l >> 4) * 4 + r;
                unsigned int p0 = cvtpk(acc[os][0][r], acc[os][1][r]);
                unsigned int p1 = cvtpk(acc[os][2][r], acc[os][3][r]);
                Pb[k * 256 + w * 64 + 0  + (l & 15)] = (ushort_t)p0;
                Pb[k * 256 + w * 64 + 16 + (l & 15)] = (ushort_t)(p0 >> 16);
                Pb[k * 256 + w * 64 + 32 + (l & 15)] = (ushort_t)p1;
                Pb[k * 256 + w * 64 + 48 + (l & 15)] = (ushort_t)(p1 >> 16);
            }
    } else {
        float* Pb = P + ((size_t)(chunk * B_ + b)) * TILE_KS;
#pragma unroll
        for (int os = 0; os < 4; ++os)
#pragma unroll
            for (int r = 0; r < 4; ++r) {
                const int k = os * 16 + (l >> 4) * 4 + r;
#pragma unroll
                for (int j = 0; j < 4; ++j)
                    Pb[k * 256 + (w * 4 + j) * 16 + (l & 15)] = acc[os][j][r];
            }
    }
}

// ---------------- MFMA: Qraw[b][n][k](bf16) = sum_s Dbf[b,k,s] * softmax_s(Rt)[b,n,s]
__global__ __launch_bounds__(256) void qt_mfma(
    const ushort_t* __restrict__ Dbf,  // [b][64][256]
    const ushort_t* __restrict__ Rraw, // [b][N][256] raw rou
    const float* __restrict__ st2r,    // [b*N] (max, invsum)
    ushort_t* __restrict__ Qraw,       // [b][N][64] bf16
    float* __restrict__ Nrm)           // [b][64], pre-zeroed
{
    __shared__ short sm[32768];
    const int t = threadIdx.x;
    const int l = t & 63, w = t >> 6;
    const int b = blockIdx.x / 36;
    const int n0 = (blockIdx.x % 36) * 256;

    const uint4* Av = (const uint4*)Dbf;
    const uint4* Xv = (const uint4*)Rraw;
    const float2* S2 = (const float2*)st2r;
    uint4* smv = (uint4*)sm;

    uint4 wreg[8], xreg[8];
    float2 sreg[8];
#pragma unroll
    for (int i = 0; i < 8; ++i) {
        int cell = i * 256 + t;
        int osub = cell >> 9, g = (cell >> 4) & 31, oi = cell & 15;
        wreg[i] = Av[(size_t)(b * 64 + osub * 16 + oi) * 32 + g];
    }
#pragma unroll
    for (int i = 0; i < 8; ++i) {
        int cell = i * 256 + t;
        int s = cell >> 7, g8 = (cell >> 4) & 7, ni = cell & 15;
        xreg[i] = Xv[((size_t)b * N_ + n0 + s * 16 + ni) * 32 + g8];
        sreg[i] = S2[(size_t)b * N_ + n0 + s * 16 + ni];  // row stats constant across stages
    }
#pragma unroll
    for (int i = 0; i < 8; ++i) smv[i * 256 + t] = wreg[i];
#pragma unroll
    for (int i = 0; i < 8; ++i) smv[2048 + i * 256 + t] = expcell(xreg[i], sreg[i]);
    __syncthreads();

    f32x4 zr = {0.f, 0.f, 0.f, 0.f};
    f32x4 acc[4][4];
#pragma unroll
    for (int i = 0; i < 4; ++i)
#pragma unroll
        for (int j = 0; j < 4; ++j) acc[i][j] = zr;

    const bf16x8* smW = (const bf16x8*)sm;
    const bf16x8* smX = (const bf16x8*)(sm + 16384);

    for (int st = 0; st < 4; ++st) {
        if (st < 3) {
#pragma unroll
            for (int i = 0; i < 8; ++i) {
                int cell = i * 256 + t;
                int s = cell >> 7, g8 = (cell >> 4) & 7, ni = cell & 15;
                xreg[i] = Xv[((size_t)b * N_ + n0 + s * 16 + ni) * 32 + (st + 1) * 8 + g8];
            }
        }
#pragma unroll
        for (int kgl = 0; kgl < 2; ++kgl) {
            const int kg = st * 2 + kgl;
            bf16x8 Af[4], Bf[4];
#pragma unroll
            for (int os = 0; os < 4; ++os)
                Af[os] = smW[(os * 32 + kg * 4 + (l >> 4)) * 16 + (l & 15)];
#pragma unroll
            for (int j = 0; j < 4; ++j)
                Bf[j] = smX[((w * 4 + j) * 8 + kgl * 4 + (l >> 4)) * 16 + (l & 15)];
#pragma unroll
            for (int os = 0; os < 4; ++os)
#pragma unroll
                for (int j = 0; j < 4; ++j)
                    acc[os][j] = __builtin_amdgcn_mfma_f32_16x16x32_bf16(Af[os], Bf[j], acc[os][j], 0, 0, 0);
        }
        __syncthreads();
        if (st < 3) {
#pragma unroll
            for (int i = 0; i < 8; ++i) smv[2048 + i * 256 + t] = expcell(xreg[i], sreg[i]);
            __syncthreads();
        }
    }

    // epilogue: nrm2 partials + [n][k] transposed bf16 stores
    float* snrm = (float*)sm + 9216;
    __syncthreads();
    if (t < 64) snrm[t] = 0.f;
    __syncthreads();
#pragma unroll
    for (int os = 0; os < 4; ++os)
#pragma unroll
        for (int r = 0; r < 4; ++r) {
            float p = 0.f;
#pragma unroll
            for (int j = 0; j < 4; ++j) p = fmaf(acc[os][j][r], acc[os][j][r], p);
#pragma unroll
            for (int m = 1; m < 16; m <<= 1) p += __shfl_xor(p, m);
            if ((l & 15) == 0) atomicAdd(&snrm[os * 16 + (l >> 4) * 4 + r], p);
        }
    float* Tw = (float*)sm + w * 2304;  // per-wave [32][72]
#pragma unroll
    for (int h = 0; h < 2; ++h) {
        __syncthreads();
#pragma unroll
        for (int os = 0; os < 4; ++os)
#pragma unroll
            for (int r = 0; r < 4; ++r) {
                const int kcol = os * 16 + (l >> 4) * 4 + r;
#pragma unroll
                for (int jj = 0; jj < 2; ++jj)
                    Tw[(jj * 16 + (l & 15)) * 72 + kcol] = acc[os][h * 2 + jj][r];
            }
        __syncthreads();
#pragma unroll
        for (int i = 0; i < 8; ++i) {
            const int lrow = i * 4 + (l >> 4);
            f32x4 v = *(const f32x4*)&Tw[lrow * 72 + (l & 15) * 4];
            uint2 uu;
            uu.x = cvtpk(v[0], v[1]);
            uu.y = cvtpk(v[2], v[3]);
            *(uint2*)&Qraw[((size_t)b * N_ + n0 + w * 64 + h * 32 + lrow) * 64 + (l & 15) * 4] = uu;
        }
    }
    __syncthreads();
    if (t < 64) atomicAdd(&Nrm[b * 64 + t], snrm[t]);
}

// ---------------- partial-sum reductions over NCHUNK
__global__ __launch_bounds__(256) void chunk_reduce_bf(
    const ushort_t* __restrict__ P, ushort_t* __restrict__ outb)
{
    const int i2 = blockIdx.x * 256 + threadIdx.x;  // uint2 cell = 4 bf16
    float s0 = 0.f, s1 = 0.f, s2 = 0.f, s3 = 0.f;
#pragma unroll
    for (int c = 0; c < NCHUNK; ++c) {
        uint2 u = ((const uint2*)P)[(size_t)c * (B_ * TILE_KS / 4) + i2];
        s0 += bf2f((ushort_t)u.x); s1 += bf2f(u.x >> 16);
        s2 += bf2f((ushort_t)u.y); s3 += bf2f(u.y >> 16);
    }
    uint2 o;
    o.x = cvtpk(s0, s1);
    o.y = cvtpk(s2, s3);
    ((uint2*)outb)[i2] = o;
}
// bf16 partials -> fp32 out (znum path; ZnT stays fp32 for z_final's norm)
__global__ __launch_bounds__(256) void chunk_reduce_b2f(
    const ushort_t* __restrict__ P, float* __restrict__ outf)
{
    const int i2 = blockIdx.x * 256 + threadIdx.x;  // uint2 cell = 4 bf16
    float s0 = 0.f, s1 = 0.f, s2 = 0.f, s3 = 0.f;
#pragma unroll
    for (int c = 0; c < NCHUNK; ++c) {
        uint2 u = ((const uint2*)P)[(size_t)c * (B_ * TILE_KS / 4) + i2];
        s0 += bf2f((ushort_t)u.x); s1 += bf2f(u.x >> 16);
        s2 += bf2f((ushort_t)u.y); s3 += bf2f(u.y >> 16);
    }
    float4 o = make_float4(s0, s1, s2, s3);
    ((float4*)outf)[i2] = o;
}

// ---------------- Q = softmax_k(Qraw * invn); write Qout[b][n][k] fp32 + Qbf[b][k][n] bf16
__global__ __launch_bounds__(256) void q_final(
    const ushort_t* __restrict__ Qraw, const float* __restrict__ Nrm,
    float* __restrict__ Qout, ushort_t* __restrict__ Qbf)
{
    __shared__ ushort_t Tq[64 * 256];
    __shared__ float invn[64];
    const int b = blockIdx.y;
    const int n0 = blockIdx.x * 256;
    const int t = threadIdx.x;
    const int l = t & 63, w = t >> 6;
    if (t < 64) invn[t] = 1.0f / fmaxf(sqrtf(Nrm[b * 64 + t]), 1e-12f);
    __syncthreads();
    const uint4* q4 = (const uint4*)(Qraw + ((size_t)b * N_ + n0 + t) * 64);
    float q[64];
#pragma unroll
    for (int kk = 0; kk < 8; ++kk) {
        uint4 u = q4[kk];
        q[kk * 8 + 0] = bf2f((ushort_t)u.x); q[kk * 8 + 1] = bf2f(u.x >> 16);
        q[kk * 8 + 2] = bf2f((ushort_t)u.y); q[kk * 8 + 3] = bf2f(u.y >> 16);
        q[kk * 8 + 4] = bf2f((ushort_t)u.z); q[kk * 8 + 5] = bf2f(u.z >> 16);
        q[kk * 8 + 6] = bf2f((ushort_t)u.w); q[kk * 8 + 7] = bf2f(u.w >> 16);
    }
    float mx = -INFINITY;
#pragma unroll
    for (int k = 0; k < 64; ++k) { q[k] *= invn[k]; mx = fmaxf(mx, q[k]); }
    float sum = 0.f;
#pragma unroll
    for (int k = 0; k < 64; ++k) { q[k] = __expf(q[k] - mx); sum += q[k]; }
    const float inv = 1.0f / sum;
    const size_t base = ((size_t)b * N_ + n0 + t) * 64;
#pragma unroll
    for (int kk = 0; kk < 16; ++kk) {
        f32x4 v = {q[kk * 4] * inv, q[kk * 4 + 1] * inv, q[kk * 4 + 2] * inv, q[kk * 4 + 3] * inv};
        *(f32x4*)&Qout[base + kk * 4] = v;
        q[kk * 4] = v[0]; q[kk * 4 + 1] = v[1]; q[kk * 4 + 2] = v[2]; q[kk * 4 + 3] = v[3];
    }
#pragma unroll
    for (int k = 0; k < 64; ++k) Tq[k * 256 + t] = f2bf(q[k]);
    __syncthreads();
#pragma unroll
    for (int kk = 0; kk < 16; ++kk) {
        const int k = kk * 4 + w;
        ushort4 v = *(const ushort4*)&Tq[k * 256 + l * 4];
        *(ushort4*)&Qbf[((size_t)b * 64 + k) * N_ + n0 + l * 4] = v;
    }
}

// ---------------- Z[b,s,k] = ZnT[b,k,s] / l2norm over s (qsum cancels in l2norm)
__global__ __launch_bounds__(256) void z_final(
    const float* __restrict__ ZnT, float* __restrict__ Z)
{
    __shared__ float red[256];
    __shared__ float invn[64];
    const int b = blockIdx.x;
    const int t = threadIdx.x;
    const float* Zb = ZnT + (size_t)b * TILE_KS;
    {
        const int k = t >> 2, qq = t & 3;
        float ss = 0.f;
        for (int j = 0; j < 64; ++j) {
            float v = Zb[k * 256 + qq * 64 + j];
            ss = fmaf(v, v, ss);
        }
        red[t] = ss;
    }
    __syncthreads();
    if ((t & 3) == 0) {
        float tot = red[t] + red[t + 1] + red[t + 2] + red[t + 3];
        invn[t >> 2] = 1.0f / fmaxf(sqrtf(tot), 1e-12f);
    }
    __syncthreads();
    {
        const int k = t & 63, w = t >> 6;
        const float sc = invn[k];
        for (int j = 0; j < 64; ++j) {
            int s = w * 64 + j;
            Z[((size_t)b * 256 + s) * 64 + k] = Zb[k * 256 + s] * sc;
        }
    }
}

extern "C" void kernel_launch(void* const* d_in, const int* in_sizes, int n_in,
                              void* d_out, int out_size, void* d_ws, size_t ws_size,
                              hipStream_t stream)
{
    const float* X       = (const float*)d_in[0];
    const float* phi_w   = (const float*)d_in[1];
    const float* phi_g   = (const float*)d_in[2];
    const float* phi_b   = (const float*)d_in[3];
    const float* phi_m   = (const float*)d_in[4];
    const float* phi_v   = (const float*)d_in[5];
    const float* theta_w = (const float*)d_in[6];
    const float* theta_g = (const float*)d_in[7];
    const float* theta_b = (const float*)d_in[8];
    const float* theta_m = (const float*)d_in[9];
    const float* theta_v = (const float*)d_in[10];
    const float* rou_w   = (const float*)d_in[11];
    const float* rou_g   = (const float*)d_in[12];
    const float* rou_b   = (const float*)d_in[13];
    const float* rou_m   = (const float*)d_in[14];
    const float* rou_v   = (const float*)d_in[15];
    const float* val_w   = (const float*)d_in[16];
    const float* val_g   = (const float*)d_in[17];
    const float* val_b   = (const float*)d_in[18];
    const float* val_m   = (const float*)d_in[19];
    const float* val_v   = (const float*)d_in[20];

    float* ws = (float*)d_ws;
    size_t off = 0;
    ushort_t* Xs  = (ushort_t*)(ws + off); off += (size_t)B_ * N_ * C_ / 2;
    ushort_t* Wt  = (ushort_t*)(ws + off); off += 832 * C_ / 2;
    float* be     = ws + off; off += 832;
    float* st2    = ws + off; off += 2 * B_ * 256;
    float* st2r   = ws + off; off += 2 * B_ * N_;
    ushort_t* Pbf = (ushort_t*)(ws + off); off += (size_t)B_ * 64 * N_ / 2;
    ushort_t* Tbf = (ushort_t*)(ws + off); off += (size_t)B_ * 256 * N_ / 2;
    ushort_t* Vbf = (ushort_t*)(ws + off); off += (size_t)B_ * 256 * N_ / 2;
    ushort_t* Rt  = (ushort_t*)(ws + off); off += (size_t)B_ * N_ * 256 / 2;
    ushort_t* Qbf = (ushort_t*)(ws + off); off += (size_t)B_ * 64 * N_ / 2;
    ushort_t* Dbf = (ushort_t*)(ws + off); off += (size_t)B_ * 64 * 256 / 2;
    float* part   = ws + off; off += (size_t)NCHUNK * B_ * TILE_KS;
    ushort_t* Qraw = (ushort_t*)(ws + off); off += (size_t)B_ * N_ * 64 / 2;
    float* ZnT    = ws + off; off += (size_t)B_ * TILE_KS;
    float* Nrm    = ws + off; off += B_ * 64;

    float* Zout = (float*)d_out;                  // B*S*K
    float* Qout = Zout + (size_t)B_ * S_ * K_;    // B*N*K

    hipMemsetAsync(Nrm, 0, B_ * 64 * sizeof(float), stream);

    prep_w<<<832, 256, 0, stream>>>(phi_w, phi_g, phi_b, phi_m, phi_v,
                                    theta_w, theta_g, theta_b, theta_m, theta_v,
                                    rou_w, rou_g, rou_b, rou_m, rou_v,
                                    val_w, val_g, val_b, val_m, val_v, Wt, be);
    xpose<<<dim3(N_ / 64, C_ / 64, B_), 256, 0, stream>>>(X, Xs);

    proj_mfma_all<<<3744, 256, 0, stream>>>(Wt, be, Xs, Pbf, Tbf, Vbf, Rt);

    rowstat_n<<<B_ * 256, 256, 0, stream>>>(Tbf, st2);
    rowstat_rt<<<B_ * N_ / 32, 256, 0, stream>>>(Rt, st2r);

    ks_mfma<<<dim3(NCHUNK, B_), 256, 0, stream>>>(Pbf, Tbf, st2, part, 1);
    chunk_reduce_bf<<<B_ * TILE_KS / 1024, 256, 0, stream>>>((const ushort_t*)part, Dbf);

    qt_mfma<<<36 * B_, 256, 0, stream>>>(Dbf, Rt, st2r, Qraw, Nrm);
    q_final<<<dim3(36, B_), 256, 0, stream>>>(Qraw, Nrm, Qout, Qbf);

    ks_mfma<<<dim3(NCHUNK, B_), 256, 0, stream>>>(Qbf, Vbf, (const float*)nullptr, part, 1);
    chunk_reduce_b2f<<<B_ * TILE_KS / 1024, 256, 0, stream>>>((const ushort_t*)part, ZnT);
    z_final<<<B_, 256, 0, stream>>>(ZnT, Zout);
}